// Round 1
// baseline (5032.859 us; speedup 1.0000x reference)
//
#include <hip/hip_runtime.h>
#include <math.h>

// MQA: B=4, S=2048, H=2048, NH=16, HD=128. All fp32.
// Pipeline:
//   P1: q = hs @ w_q + b_q          -> d_out used as scratch [8192][2048]
//   P2: k = hs @ w_k + b_k          -> ws                    [8192][128]
//   P3: v = hs @ w_v + b_v          -> ws                    [8192][128]
//   P4: flash attention per (b,nh,qblk); writes T[b][nh*128+hd][s] -> ws [4][2048][2048]
//       (this matches reference's swapaxes(-1,-2).reshape: row index = hidden, col = seq)
//   P5: out = T @ w_o + b_o         -> d_out [8192][2048]  (contracts over seq!)

#define BATCH 4
#define SLEN 2048
#define HDIM 2048
#define NHEADS 16
#define HD 128

// ---------------------------------------------------------------------------
// Tiled fp32 GEMM + bias: C[M][N] = A[M][K] @ B[K][N] + bias[N]
// BM=BN=128, BK=8, 256 threads, 8x8 microtile per thread.
// Requires M%128==0, N%128==0 or N==128, K%8==0.
// ---------------------------------------------------------------------------
__global__ __launch_bounds__(256) void sgemm_bias(
    const float* __restrict__ A, const float* __restrict__ B,
    const float* __restrict__ bias, float* __restrict__ C,
    int M, int N, int K)
{
    __shared__ float As[8][128];   // As[k][m]
    __shared__ float Bs[8][128];   // Bs[k][n]

    const int t  = threadIdx.x;
    const int tx = t & 15;         // 16 cols of threads
    const int ty = t >> 4;         // 16 rows of threads
    const int bm = blockIdx.y << 7;
    const int bn = blockIdx.x << 7;

    float acc[8][8];
#pragma unroll
    for (int i = 0; i < 8; ++i)
#pragma unroll
        for (int j = 0; j < 8; ++j) acc[i][j] = 0.f;

    const int arow = t >> 1;            // 0..127
    const int acol = (t & 1) << 2;      // 0 or 4
    const int brow = t >> 5;            // 0..7
    const int bcol = (t & 31) << 2;     // 0..124

    const float* Aptr = A + (size_t)(bm + arow) * K + acol;
    const float* Bptr = B + (size_t)brow * N + bn + bcol;

    for (int k0 = 0; k0 < K; k0 += 8) {
        float4 a4 = *reinterpret_cast<const float4*>(Aptr + k0);
        float4 b4 = *reinterpret_cast<const float4*>(Bptr + (size_t)k0 * N);
        As[acol + 0][arow] = a4.x;
        As[acol + 1][arow] = a4.y;
        As[acol + 2][arow] = a4.z;
        As[acol + 3][arow] = a4.w;
        *reinterpret_cast<float4*>(&Bs[brow][bcol]) = b4;
        __syncthreads();

#pragma unroll
        for (int k = 0; k < 8; ++k) {
            float4 a0 = *reinterpret_cast<const float4*>(&As[k][ty << 3]);
            float4 a1 = *reinterpret_cast<const float4*>(&As[k][(ty << 3) + 4]);
            float4 b0 = *reinterpret_cast<const float4*>(&Bs[k][tx << 3]);
            float4 b1 = *reinterpret_cast<const float4*>(&Bs[k][(tx << 3) + 4]);
            float ar[8] = {a0.x, a0.y, a0.z, a0.w, a1.x, a1.y, a1.z, a1.w};
            float br[8] = {b0.x, b0.y, b0.z, b0.w, b1.x, b1.y, b1.z, b1.w};
#pragma unroll
            for (int i = 0; i < 8; ++i)
#pragma unroll
                for (int j = 0; j < 8; ++j)
                    acc[i][j] = fmaf(ar[i], br[j], acc[i][j]);
        }
        __syncthreads();
    }

    float bv[8];
#pragma unroll
    for (int j = 0; j < 8; ++j) bv[j] = bias[bn + (tx << 3) + j];

#pragma unroll
    for (int i = 0; i < 8; ++i) {
        const int row = bm + (ty << 3) + i;
        float4 o0 = make_float4(acc[i][0] + bv[0], acc[i][1] + bv[1],
                                acc[i][2] + bv[2], acc[i][3] + bv[3]);
        float4 o1 = make_float4(acc[i][4] + bv[4], acc[i][5] + bv[5],
                                acc[i][6] + bv[6], acc[i][7] + bv[7]);
        float4* Cp = reinterpret_cast<float4*>(&C[(size_t)row * N + bn + (tx << 3)]);
        Cp[0] = o0;
        Cp[1] = o1;
    }
}

// ---------------------------------------------------------------------------
// Flash attention (fp32, online softmax), MQA: one KV head shared by 16 Q heads.
// Block = (b, nh, qblk of 64 rows). 256 threads as 16x16:
//   thread(tx,ty): S-tile rows 4*ty..4*ty+3, S-cols 2*tx..2*tx+1, O-cols 8*tx..8*tx+7
// Output written TRANSPOSED: T[b][nh*128+d][s]  (seq is the contracted dim of P5)
// ---------------------------------------------------------------------------
__global__ __launch_bounds__(256) void mqa_attn(
    const float* __restrict__ q,   // [8192][2048]  (b,s) x (nh*128+hd)
    const float* __restrict__ kx,  // [8192][128]
    const float* __restrict__ vx,  // [8192][128]
    float* __restrict__ T)         // [4][2048][2048]
{
    __shared__ float Qs[64][132];  // padded stride vs bank conflicts
    __shared__ float Ks[32][132];
    __shared__ float Vs[32][132];
    __shared__ float Ps[64][33];

    const int t  = threadIdx.x;
    const int tx = t & 15;
    const int ty = t >> 4;

    const int bid = blockIdx.x;
    const int qb  = bid & 31;          // 32 q-blocks of 64
    const int nh  = (bid >> 5) & 15;
    const int b   = bid >> 9;
    const int s0  = qb << 6;

    // ---- load Q tile [64][128] ----
    {
        const int base_row = b * SLEN + s0;
        const int base_col = nh * HD;
#pragma unroll
        for (int u = 0; u < 8; ++u) {
            int fi  = u * 256 + t;         // 0..2047 float4 slots
            int row = fi >> 5;             // 0..63
            int c4  = fi & 31;             // 0..31
            float4 qv = *reinterpret_cast<const float4*>(
                &q[(size_t)(base_row + row) * HDIM + base_col + (c4 << 2)]);
            *reinterpret_cast<float4*>(&Qs[row][c4 << 2]) = qv;
        }
    }

    float O[4][8];
    float m[4], l[4];
#pragma unroll
    for (int i = 0; i < 4; ++i) {
        m[i] = -INFINITY;
        l[i] = 0.f;
#pragma unroll
        for (int d = 0; d < 8; ++d) O[i][d] = 0.f;
    }

    const float scale = 0.08838834764831845f;  // 1/sqrt(128)
    const float4* Qs4 = reinterpret_cast<const float4*>(Qs);
    const float4* Ks4 = reinterpret_cast<const float4*>(Ks);
    const float4* Vs4 = reinterpret_cast<const float4*>(Vs);

    for (int kb = 0; kb < SLEN / 32; ++kb) {
        __syncthreads();   // protect Ks/Vs/Ps from previous iteration's readers
        // ---- load K,V chunk [32][128] ----
        {
            const int krow0 = b * SLEN + (kb << 5);
#pragma unroll
            for (int u = 0; u < 4; ++u) {
                int fi  = u * 256 + t;     // 0..1023
                int row = fi >> 5;         // 0..31
                int c4  = fi & 31;
                float4 kv = *reinterpret_cast<const float4*>(
                    &kx[(size_t)(krow0 + row) * HD + (c4 << 2)]);
                float4 vv = *reinterpret_cast<const float4*>(
                    &vx[(size_t)(krow0 + row) * HD + (c4 << 2)]);
                *reinterpret_cast<float4*>(&Ks[row][c4 << 2]) = kv;
                *reinterpret_cast<float4*>(&Vs[row][c4 << 2]) = vv;
            }
        }
        __syncthreads();

        // ---- S = scale * Q K^T : thread computes 4x2 ----
        float sv[4][2] = {{0.f, 0.f}, {0.f, 0.f}, {0.f, 0.f}, {0.f, 0.f}};
#pragma unroll 8
        for (int d4 = 0; d4 < 32; ++d4) {
            float4 qv[4], kv[2];
#pragma unroll
            for (int i = 0; i < 4; ++i) qv[i] = Qs4[((ty << 2) + i) * 33 + d4];
#pragma unroll
            for (int j = 0; j < 2; ++j) kv[j] = Ks4[((tx << 1) + j) * 33 + d4];
#pragma unroll
            for (int i = 0; i < 4; ++i)
#pragma unroll
                for (int j = 0; j < 2; ++j) {
                    sv[i][j] = fmaf(qv[i].x, kv[j].x, sv[i][j]);
                    sv[i][j] = fmaf(qv[i].y, kv[j].y, sv[i][j]);
                    sv[i][j] = fmaf(qv[i].z, kv[j].z, sv[i][j]);
                    sv[i][j] = fmaf(qv[i].w, kv[j].w, sv[i][j]);
                }
        }

        // ---- online softmax update ----
#pragma unroll
        for (int i = 0; i < 4; ++i) {
            float s0v = sv[i][0] * scale;
            float s1v = sv[i][1] * scale;
            float tm = fmaxf(s0v, s1v);
            tm = fmaxf(tm, __shfl_xor(tm, 1));
            tm = fmaxf(tm, __shfl_xor(tm, 2));
            tm = fmaxf(tm, __shfl_xor(tm, 4));
            tm = fmaxf(tm, __shfl_xor(tm, 8));
            float mnew  = fmaxf(m[i], tm);
            float alpha = __expf(m[i] - mnew);   // 0 on first chunk (m=-inf)
            float p0 = __expf(s0v - mnew);
            float p1 = __expf(s1v - mnew);
            float rs = p0 + p1;
            rs += __shfl_xor(rs, 1);
            rs += __shfl_xor(rs, 2);
            rs += __shfl_xor(rs, 4);
            rs += __shfl_xor(rs, 8);
            l[i] = l[i] * alpha + rs;
            m[i] = mnew;
#pragma unroll
            for (int d = 0; d < 8; ++d) O[i][d] *= alpha;
            Ps[(ty << 2) + i][(tx << 1) + 0] = p0;
            Ps[(ty << 2) + i][(tx << 1) + 1] = p1;
        }
        __syncthreads();

        // ---- O += P @ V : thread owns rows 4ty.., cols 8tx.. ----
#pragma unroll 8
        for (int kk = 0; kk < 32; ++kk) {
            float4 v0 = Vs4[kk * 33 + (tx << 1)];
            float4 v1 = Vs4[kk * 33 + (tx << 1) + 1];
#pragma unroll
            for (int i = 0; i < 4; ++i) {
                float pi = Ps[(ty << 2) + i][kk];
                O[i][0] = fmaf(pi, v0.x, O[i][0]);
                O[i][1] = fmaf(pi, v0.y, O[i][1]);
                O[i][2] = fmaf(pi, v0.z, O[i][2]);
                O[i][3] = fmaf(pi, v0.w, O[i][3]);
                O[i][4] = fmaf(pi, v1.x, O[i][4]);
                O[i][5] = fmaf(pi, v1.y, O[i][5]);
                O[i][6] = fmaf(pi, v1.z, O[i][6]);
                O[i][7] = fmaf(pi, v1.w, O[i][7]);
            }
        }
    }

    // ---- normalize and store transposed: T[b][nh*128+d][s0+row] ----
#pragma unroll
    for (int i = 0; i < 4; ++i) {
        float invl = 1.0f / l[i];
        int srow = s0 + (ty << 2) + i;
#pragma unroll
        for (int dd = 0; dd < 8; ++dd) {
            int d = (tx << 3) + dd;
            T[((size_t)b * HDIM + nh * HD + d) * SLEN + srow] = O[i][dd] * invl;
        }
    }
}

// ---------------------------------------------------------------------------
extern "C" void kernel_launch(void* const* d_in, const int* in_sizes, int n_in,
                              void* d_out, int out_size, void* d_ws, size_t ws_size,
                              hipStream_t stream) {
    const float* hs  = (const float*)d_in[0];
    const float* w_q = (const float*)d_in[1];
    const float* b_q = (const float*)d_in[2];
    const float* w_k = (const float*)d_in[3];
    const float* b_k = (const float*)d_in[4];
    const float* w_v = (const float*)d_in[5];
    const float* b_v = (const float*)d_in[6];
    const float* w_o = (const float*)d_in[7];
    const float* b_o = (const float*)d_in[8];
    float* out = (float*)d_out;

    const int M = BATCH * SLEN;  // 8192

    float* k_ws = (float*)d_ws;                  //  4 MB
    float* v_ws = k_ws + (size_t)M * HD;         //  4 MB
    float* T_ws = v_ws + (size_t)M * HD;         // 64 MB
    float* qbuf = out;                           // reuse d_out as q scratch

    dim3 blk(256);
    // P1: Q projection -> d_out
    sgemm_bias<<<dim3(HDIM / 128, M / 128), blk, 0, stream>>>(
        hs, w_q, b_q, qbuf, M, HDIM, HDIM);
    // P2/P3: K,V projections -> ws
    sgemm_bias<<<dim3(1, M / 128), blk, 0, stream>>>(
        hs, w_k, b_k, k_ws, M, HD, HDIM);
    sgemm_bias<<<dim3(1, M / 128), blk, 0, stream>>>(
        hs, w_v, b_v, v_ws, M, HD, HDIM);
    // P4: fused flash attention -> T (transposed layout)
    mqa_attn<<<dim3(BATCH * NHEADS * (SLEN / 64)), blk, 0, stream>>>(
        qbuf, k_ws, v_ws, T_ws);
    // P5: O projection (contracts over seq) -> d_out
    sgemm_bias<<<dim3(HDIM / 128, M / 128), blk, 0, stream>>>(
        T_ws, w_o, b_o, out, M, HDIM, HDIM);
}

// Round 5
// 1004.784 us; speedup vs baseline: 5.0089x; 5.0089x over previous
//
#include <hip/hip_runtime.h>
#include <math.h>

// MQA bf16-MFMA pipeline. B=4, S=2048, H=2048, NH=16, HD=128.
//  conv:  hs f32 -> hs_bf16 (d_out lo half)
//  convT: w_q/w_k/w_v/w_o f32 [K][N] -> bf16 [N][K] (ws)
//  P1: Q = hs @ w_q + b_q   bf16 out -> d_out hi half
//  P2: K = hs @ w_k + b_k   bf16 out -> ws
//  P3: V = hs @ w_v + b_v   bf16 out -> ws ; then transpose -> VT[b][d][s]
//  P4: flash attn (MFMA) -> T[b][nh*128+d][s] bf16 (ws)
//  P5: out = T @ w_o + b_o  f32 -> d_out

#define BATCH 4
#define SLEN 2048
#define HDIM 2048
#define NHEADS 16
#define HD 128

typedef __bf16 bf16x8 __attribute__((ext_vector_type(8)));
typedef float f32x4 __attribute__((ext_vector_type(4)));

__device__ __forceinline__ void gload_lds16(const void* g, void* l) {
    __builtin_amdgcn_global_load_lds(
        (const __attribute__((address_space(1))) void*)g,
        (__attribute__((address_space(3))) void*)l, 16, 0, 0);
}

// ---------------------------------------------------------------------------
// conv: f32 -> bf16, 8 elems/thread
// ---------------------------------------------------------------------------
__global__ void conv_bf16(const float* __restrict__ in, __bf16* __restrict__ out) {
    int i = (blockIdx.x * 256 + threadIdx.x) * 8;
    float4 a = *reinterpret_cast<const float4*>(in + i);
    float4 b = *reinterpret_cast<const float4*>(in + i + 4);
    bf16x8 o;
    o[0] = (__bf16)a.x; o[1] = (__bf16)a.y; o[2] = (__bf16)a.z; o[3] = (__bf16)a.w;
    o[4] = (__bf16)b.x; o[5] = (__bf16)b.y; o[6] = (__bf16)b.z; o[7] = (__bf16)b.w;
    *reinterpret_cast<bf16x8*>(out + i) = o;
}

// ---------------------------------------------------------------------------
// transpose+convert: in f32 [R][C] -> out bf16 [C][R]
// ---------------------------------------------------------------------------
__global__ void transpose_conv(const float* __restrict__ in, __bf16* __restrict__ out,
                               int R, int C) {
    __shared__ float tile[32][33];
    int c0 = blockIdx.x * 32, r0 = blockIdx.y * 32;
    int tr = threadIdx.x >> 5, tc = threadIdx.x & 31;
#pragma unroll
    for (int i = 0; i < 4; ++i)
        tile[tr + i * 8][tc] = in[(size_t)(r0 + tr + i * 8) * C + c0 + tc];
    __syncthreads();
#pragma unroll
    for (int i = 0; i < 4; ++i)
        out[(size_t)(c0 + tr + i * 8) * R + r0 + tc] = (__bf16)tile[tc][tr + i * 8];
}

// ---------------------------------------------------------------------------
// V bf16 [b][2048][128] -> VT bf16 [b][128][2048]
// ---------------------------------------------------------------------------
__global__ void transpose_v(const __bf16* __restrict__ in, __bf16* __restrict__ out) {
    __shared__ __bf16 tile[32][33];
    int b = blockIdx.z;
    int d0 = blockIdx.x * 32, s0 = blockIdx.y * 32;
    int tr = threadIdx.x >> 5, tc = threadIdx.x & 31;
    const __bf16* inb = in + (size_t)b * SLEN * HD;
    __bf16* outb = out + (size_t)b * HD * SLEN;
#pragma unroll
    for (int i = 0; i < 4; ++i)
        tile[tr + i * 8][tc] = inb[(size_t)(s0 + tr + i * 8) * HD + d0 + tc];
    __syncthreads();
#pragma unroll
    for (int i = 0; i < 4; ++i)
        outb[(size_t)(d0 + tr + i * 8) * SLEN + s0 + tc] = tile[tc][tr + i * 8];
}

// ---------------------------------------------------------------------------
// bf16 GEMM (m97 structure): C[M][N] = A[M][K] @ BT[N][K]^T + bias
// 128x128 tile, BK=64, 4 waves (2x2), each wave 64x64 (4x4 of 16x16x32 frags)
// ---------------------------------------------------------------------------
template <bool BF16_OUT>
__global__ __launch_bounds__(256) void gemm_bt(
    const __bf16* __restrict__ A, const __bf16* __restrict__ BT,
    const float* __restrict__ bias, void* __restrict__ Cout,
    int M, int N, int K)
{
    __shared__ __bf16 As[128 * 64];
    __shared__ __bf16 Bs[128 * 64];
    const int t = threadIdx.x;
    const int lane = t & 63;
    const int w = t >> 6;
    const int wr = w >> 1, wc = w & 1;
    const int m0 = blockIdx.y << 7, n0 = blockIdx.x << 7;

    f32x4 acc[4][4] = {};
    const int l8 = (lane & 7) * 8;   // k-offset (elems) within chunk row
    const int lr = lane >> 3;        // row-in-chunk

    for (int k0 = 0; k0 < K; k0 += 64) {
        __syncthreads();
#pragma unroll
        for (int i = 0; i < 4; ++i) {
            int c = w * 4 + i;
            int row = c * 8 + lr;
            gload_lds16(A + (size_t)(m0 + row) * K + k0 + l8, (char*)As + c * 1024);
            gload_lds16(BT + (size_t)(n0 + row) * K + k0 + l8, (char*)Bs + c * 1024);
        }
        __syncthreads();
#pragma unroll
        for (int ks = 0; ks < 2; ++ks) {
            bf16x8 a[4], b[4];
#pragma unroll
            for (int i = 0; i < 4; ++i) {
                a[i] = *reinterpret_cast<const bf16x8*>(
                    As + (wr * 64 + i * 16 + (lane & 15)) * 64 + ks * 32 + (lane >> 4) * 8);
                b[i] = *reinterpret_cast<const bf16x8*>(
                    Bs + (wc * 64 + i * 16 + (lane & 15)) * 64 + ks * 32 + (lane >> 4) * 8);
            }
#pragma unroll
            for (int i = 0; i < 4; ++i)
#pragma unroll
                for (int j = 0; j < 4; ++j)
                    acc[i][j] = __builtin_amdgcn_mfma_f32_16x16x32_bf16(
                        a[i], b[j], acc[i][j], 0, 0, 0);
        }
    }

    const int col_l = lane & 15, rgrp = lane >> 4;
#pragma unroll
    for (int j = 0; j < 4; ++j) {
        int col = n0 + wc * 64 + j * 16 + col_l;
        float bv = bias[col];
#pragma unroll
        for (int i = 0; i < 4; ++i) {
            int rowb = m0 + wr * 64 + i * 16 + rgrp * 4;
#pragma unroll
            for (int r = 0; r < 4; ++r) {
                float v = acc[i][j][r] + bv;
                if (BF16_OUT)
                    ((__bf16*)Cout)[(size_t)(rowb + r) * N + col] = (__bf16)v;
                else
                    ((float*)Cout)[(size_t)(rowb + r) * N + col] = v;
            }
        }
    }
}

// ---------------------------------------------------------------------------
// Flash attention, bf16 MFMA. Block = (b, nh, q-tile of 64). 4 waves, each
// owns 16 q-rows. KV tile = 64. Q in regs; K/VT staged to padded LDS;
// P via LDS; O accum fp32; writes T[b][nh*128+d][s] bf16 via LDS transpose.
// ---------------------------------------------------------------------------
__global__ __launch_bounds__(256) void mqa_attn_mfma(
    const __bf16* __restrict__ Q,   // [8192][2048]
    const __bf16* __restrict__ K,   // [8192][128]
    const __bf16* __restrict__ VT,  // [4][128][2048]
    __bf16* __restrict__ T)         // [4][2048][2048]
{
    __shared__ __bf16 Ks[64][136];      // pad: stride 272B
    __shared__ __bf16 Vt[128][72];      // pad: stride 144B (also reused as O^T)
    __shared__ __bf16 Ps[4][16][72];

    const int t = threadIdx.x;
    const int lane = t & 63;
    const int w = t >> 6;
    const int bid = blockIdx.x;
    const int qb = bid & 31;
    const int nh = (bid >> 5) & 15;
    const int b = bid >> 9;
    const int q0 = qb << 6;

    const int cl = lane & 15;        // col-in-frag / A-row
    const int rg = lane >> 4;        // k-group / C-row-group

    // Q fragments (held in registers for the whole kernel)
    bf16x8 qf[4];
    {
        const __bf16* qrow = Q + (size_t)(b * SLEN + q0 + w * 16 + cl) * HDIM
                             + nh * HD + rg * 8;
#pragma unroll
        for (int ks = 0; ks < 4; ++ks)
            qf[ks] = *reinterpret_cast<const bf16x8*>(qrow + ks * 32);
    }

    f32x4 O[8] = {};
    float m[4], l[4];
#pragma unroll
    for (int r = 0; r < 4; ++r) { m[r] = -__builtin_inff(); l[r] = 0.f; }

    const float scale = 0.08838834764831845f;  // 1/sqrt(128)

    // prefetch tile 0 into regs
    float4 kd[4], vd[4];
    {
        const size_t kbase = (size_t)(b * SLEN) * HD;
#pragma unroll
        for (int i = 0; i < 4; ++i) {
            int id = i * 256 + t;
            int r = id >> 4, c = id & 15;
            kd[i] = *reinterpret_cast<const float4*>(K + kbase + (size_t)r * HD + c * 8);
        }
#pragma unroll
        for (int i = 0; i < 4; ++i) {
            int id = i * 256 + t;
            int r = id >> 3, c = id & 7;
            vd[i] = *reinterpret_cast<const float4*>(
                VT + (size_t)(b * HD + r) * SLEN + c * 8);
        }
    }

    for (int kk = 0; kk < SLEN; kk += 64) {
        __syncthreads();   // previous compute done reading Ks/Vt
        // commit staged regs to LDS
#pragma unroll
        for (int i = 0; i < 4; ++i) {
            int id = i * 256 + t;
            int r = id >> 4, c = id & 15;
            *reinterpret_cast<float4*>(&Ks[r][c * 8]) = kd[i];
        }
#pragma unroll
        for (int i = 0; i < 4; ++i) {
            int id = i * 256 + t;
            int r = id >> 3, c = id & 7;
            *reinterpret_cast<float4*>(&Vt[r][c * 8]) = vd[i];
        }
        __syncthreads();

        // prefetch next tile (overlaps with compute below)
        if (kk + 64 < SLEN) {
            const size_t kbase = (size_t)(b * SLEN + kk + 64) * HD;
#pragma unroll
            for (int i = 0; i < 4; ++i) {
                int id = i * 256 + t;
                int r = id >> 4, c = id & 15;
                kd[i] = *reinterpret_cast<const float4*>(K + kbase + (size_t)r * HD + c * 8);
            }
#pragma unroll
            for (int i = 0; i < 4; ++i) {
                int id = i * 256 + t;
                int r = id >> 3, c = id & 7;
                vd[i] = *reinterpret_cast<const float4*>(
                    VT + (size_t)(b * HD + r) * SLEN + kk + 64 + c * 8);
            }
        }

        // ---- S = Q K^T (per wave: 16 x 64) ----
        f32x4 s[4] = {};
#pragma unroll
        for (int cb = 0; cb < 4; ++cb)
#pragma unroll
            for (int ks = 0; ks < 4; ++ks) {
                bf16x8 kf = *reinterpret_cast<const bf16x8*>(
                    &Ks[cb * 16 + cl][ks * 32 + rg * 8]);
                s[cb] = __builtin_amdgcn_mfma_f32_16x16x32_bf16(qf[ks], kf, s[cb], 0, 0, 0);
            }

        // ---- online softmax ----
#pragma unroll
        for (int cb = 0; cb < 4; ++cb)
#pragma unroll
            for (int r = 0; r < 4; ++r) s[cb][r] *= scale;

        float rs[4];
#pragma unroll
        for (int r = 0; r < 4; ++r) {
            float tm = fmaxf(fmaxf(s[0][r], s[1][r]), fmaxf(s[2][r], s[3][r]));
            tm = fmaxf(tm, __shfl_xor(tm, 1));
            tm = fmaxf(tm, __shfl_xor(tm, 2));
            tm = fmaxf(tm, __shfl_xor(tm, 4));
            tm = fmaxf(tm, __shfl_xor(tm, 8));
            float mn = fmaxf(m[r], tm);
            float alpha = __expf(m[r] - mn);
            m[r] = mn;
            l[r] *= alpha;
#pragma unroll
            for (int dcb = 0; dcb < 8; ++dcb) O[dcb][r] *= alpha;
            rs[r] = 0.f;
        }
#pragma unroll
        for (int cb = 0; cb < 4; ++cb)
#pragma unroll
            for (int r = 0; r < 4; ++r) {
                float p = __expf(s[cb][r] - m[r]);
                rs[r] += p;
                Ps[w][rg * 4 + r][cb * 16 + cl] = (__bf16)p;
            }
#pragma unroll
        for (int r = 0; r < 4; ++r) {
            float v = rs[r];
            v += __shfl_xor(v, 1);
            v += __shfl_xor(v, 2);
            v += __shfl_xor(v, 4);
            v += __shfl_xor(v, 8);
            l[r] += v;
        }
        __syncthreads();   // P visible (and orders vs next staging)

        // ---- O += P @ V ----
        bf16x8 pf[2];
#pragma unroll
        for (int ks = 0; ks < 2; ++ks)
            pf[ks] = *reinterpret_cast<const bf16x8*>(&Ps[w][cl][ks * 32 + rg * 8]);
#pragma unroll
        for (int dcb = 0; dcb < 8; ++dcb)
#pragma unroll
            for (int ks = 0; ks < 2; ++ks) {
                bf16x8 vf = *reinterpret_cast<const bf16x8*>(
                    &Vt[dcb * 16 + cl][ks * 32 + rg * 8]);
                O[dcb] = __builtin_amdgcn_mfma_f32_16x16x32_bf16(pf[ks], vf, O[dcb], 0, 0, 0);
            }
    }

    // ---- epilogue: normalize, transpose via LDS (reuse Vt), write T ----
    __syncthreads();
    float invl[4];
#pragma unroll
    for (int r = 0; r < 4; ++r) invl[r] = 1.0f / l[r];
#pragma unroll
    for (int dcb = 0; dcb < 8; ++dcb)
#pragma unroll
        for (int r = 0; r < 4; ++r)
            Vt[dcb * 16 + cl][w * 16 + rg * 4 + r] = (__bf16)(O[dcb][r] * invl[r]);
    __syncthreads();
#pragma unroll
    for (int i = 0; i < 4; ++i) {
        int id = i * 256 + t;
        int d = id >> 3, c = id & 7;
        float4 v = *reinterpret_cast<const float4*>(&Vt[d][c * 8]);
        *reinterpret_cast<float4*>(
            T + (size_t)(b * HDIM + nh * HD + d) * SLEN + q0 + c * 8) = v;
    }
}

// ---------------------------------------------------------------------------
extern "C" void kernel_launch(void* const* d_in, const int* in_sizes, int n_in,
                              void* d_out, int out_size, void* d_ws, size_t ws_size,
                              hipStream_t stream) {
    const float* hs  = (const float*)d_in[0];
    const float* w_q = (const float*)d_in[1];
    const float* b_q = (const float*)d_in[2];
    const float* w_k = (const float*)d_in[3];
    const float* b_k = (const float*)d_in[4];
    const float* w_v = (const float*)d_in[5];
    const float* b_v = (const float*)d_in[6];
    const float* w_o = (const float*)d_in[7];
    const float* b_o = (const float*)d_in[8];

    const int M = BATCH * SLEN;          // 8192
    const size_t MH = (size_t)M * HDIM;  // 16.8M

    // d_out (67.1 MB) partition: [hs_bf16 33.55MB][Q 33.55MB]
    __bf16* hs_b = (__bf16*)d_out;
    __bf16* Qb   = hs_b + MH;

    // ws partition (57.7 MB total)
    char* p = (char*)d_ws;
    __bf16* wqT = (__bf16*)p;             p += (size_t)HDIM * HDIM * 2;  // 8.39MB
    __bf16* woT = (__bf16*)p;             p += (size_t)HDIM * HDIM * 2;  // 8.39MB
    __bf16* wkT = (__bf16*)p;             p += (size_t)HD * HDIM * 2;    // 0.52MB
    __bf16* wvT = (__bf16*)p;             p += (size_t)HD * HDIM * 2;    // 0.52MB
    __bf16* Kb  = (__bf16*)p;             p += (size_t)M * HD * 2;       // 2.10MB
    __bf16* Vb  = (__bf16*)p;             p += (size_t)M * HD * 2;       // 2.10MB
    __bf16* VTb = (__bf16*)p;             p += (size_t)M * HD * 2;       // 2.10MB
    __bf16* Tb  = (__bf16*)p;                                            // 33.55MB

    dim3 blk(256);

    // converts
    conv_bf16<<<dim3(MH / (256 * 8)), blk, 0, stream>>>(hs, hs_b);
    transpose_conv<<<dim3(HDIM / 32, HDIM / 32), blk, 0, stream>>>(w_q, wqT, HDIM, HDIM);
    transpose_conv<<<dim3(HD / 32, HDIM / 32), blk, 0, stream>>>(w_k, wkT, HDIM, HD);
    transpose_conv<<<dim3(HD / 32, HDIM / 32), blk, 0, stream>>>(w_v, wvT, HDIM, HD);
    transpose_conv<<<dim3(HDIM / 32, HDIM / 32), blk, 0, stream>>>(w_o, woT, HDIM, HDIM);

    // projections
    gemm_bt<true><<<dim3(HDIM / 128, M / 128), blk, 0, stream>>>(
        hs_b, wqT, b_q, Qb, M, HDIM, HDIM);
    gemm_bt<true><<<dim3(HD / 128, M / 128), blk, 0, stream>>>(
        hs_b, wkT, b_k, Kb, M, HD, HDIM);
    gemm_bt<true><<<dim3(HD / 128, M / 128), blk, 0, stream>>>(
        hs_b, wvT, b_v, Vb, M, HD, HDIM);
    transpose_v<<<dim3(HD / 32, SLEN / 32, BATCH), blk, 0, stream>>>(Vb, VTb);

    // attention
    mqa_attn_mfma<<<dim3(BATCH * NHEADS * (SLEN / 64)), blk, 0, stream>>>(
        Qb, Kb, VTb, Tb);

    // output projection (contracts over seq via T layout)
    gemm_bt<false><<<dim3(HDIM / 128, M / 128), blk, 0, stream>>>(
        Tb, woT, b_o, d_out, M, HDIM, HDIM);
}

// Round 6
// 763.950 us; speedup vs baseline: 6.5879x; 1.3152x over previous
//
#include <hip/hip_runtime.h>
#include <math.h>

// MQA bf16-MFMA pipeline. B=4, S=2048, H=2048, NH=16, HD=128.
//  conv:  hs f32 -> hs_bf16 (d_out lo half)
//  convT: w_q/w_k/w_v/w_o f32 [K][N] -> bf16 [N][K] (ws)
//  P1: Q = hs @ w_q + b_q   bf16 out -> d_out hi half
//  P2: K = hs @ w_k + b_k   bf16 out -> ws
//  P3: V = hs @ w_v + b_v   bf16 out -> ws ; then transpose -> VT[b][d][s]
//  P4: flash attn (MFMA, QBLK=128, 8 waves) -> T[b][nh*128+d][s] bf16 (ws)
//  P5: out = T @ w_o + b_o  f32 -> d_out

#define BATCH 4
#define SLEN 2048
#define HDIM 2048
#define NHEADS 16
#define HD 128

typedef __bf16 bf16x8 __attribute__((ext_vector_type(8)));
typedef float f32x4 __attribute__((ext_vector_type(4)));

__device__ __forceinline__ void gload_lds16(const void* g, void* l) {
    __builtin_amdgcn_global_load_lds(
        (const __attribute__((address_space(1))) void*)g,
        (__attribute__((address_space(3))) void*)l, 16, 0, 0);
}

// ---------------------------------------------------------------------------
// conv: f32 -> bf16, 8 elems/thread
// ---------------------------------------------------------------------------
__global__ void conv_bf16(const float* __restrict__ in, __bf16* __restrict__ out) {
    int i = (blockIdx.x * 256 + threadIdx.x) * 8;
    float4 a = *reinterpret_cast<const float4*>(in + i);
    float4 b = *reinterpret_cast<const float4*>(in + i + 4);
    bf16x8 o;
    o[0] = (__bf16)a.x; o[1] = (__bf16)a.y; o[2] = (__bf16)a.z; o[3] = (__bf16)a.w;
    o[4] = (__bf16)b.x; o[5] = (__bf16)b.y; o[6] = (__bf16)b.z; o[7] = (__bf16)b.w;
    *reinterpret_cast<bf16x8*>(out + i) = o;
}

// ---------------------------------------------------------------------------
// transpose+convert: in f32 [R][C] -> out bf16 [C][R]
// ---------------------------------------------------------------------------
__global__ void transpose_conv(const float* __restrict__ in, __bf16* __restrict__ out,
                               int R, int C) {
    __shared__ float tile[32][33];
    int c0 = blockIdx.x * 32, r0 = blockIdx.y * 32;
    int tr = threadIdx.x >> 5, tc = threadIdx.x & 31;
#pragma unroll
    for (int i = 0; i < 4; ++i)
        tile[tr + i * 8][tc] = in[(size_t)(r0 + tr + i * 8) * C + c0 + tc];
    __syncthreads();
#pragma unroll
    for (int i = 0; i < 4; ++i)
        out[(size_t)(c0 + tr + i * 8) * R + r0 + tc] = (__bf16)tile[tc][tr + i * 8];
}

// ---------------------------------------------------------------------------
// V bf16 [b][2048][128] -> VT bf16 [b][128][2048]
// ---------------------------------------------------------------------------
__global__ void transpose_v(const __bf16* __restrict__ in, __bf16* __restrict__ out) {
    __shared__ __bf16 tile[32][33];
    int b = blockIdx.z;
    int d0 = blockIdx.x * 32, s0 = blockIdx.y * 32;
    int tr = threadIdx.x >> 5, tc = threadIdx.x & 31;
    const __bf16* inb = in + (size_t)b * SLEN * HD;
    __bf16* outb = out + (size_t)b * HD * SLEN;
#pragma unroll
    for (int i = 0; i < 4; ++i)
        tile[tr + i * 8][tc] = inb[(size_t)(s0 + tr + i * 8) * HD + d0 + tc];
    __syncthreads();
#pragma unroll
    for (int i = 0; i < 4; ++i)
        outb[(size_t)(d0 + tr + i * 8) * SLEN + s0 + tc] = tile[tc][tr + i * 8];
}

// ---------------------------------------------------------------------------
// bf16 GEMM (m97 structure): C[M][N] = A[M][K] @ BT[N][K]^T + bias
// 128x128 tile, BK=64, 4 waves (2x2), each wave 64x64 (4x4 of 16x16x32 frags)
// ---------------------------------------------------------------------------
template <bool BF16_OUT>
__global__ __launch_bounds__(256) void gemm_bt(
    const __bf16* __restrict__ A, const __bf16* __restrict__ BT,
    const float* __restrict__ bias, void* __restrict__ Cout,
    int M, int N, int K)
{
    __shared__ __bf16 As[128 * 64];
    __shared__ __bf16 Bs[128 * 64];
    const int t = threadIdx.x;
    const int lane = t & 63;
    const int w = t >> 6;
    const int wr = w >> 1, wc = w & 1;
    const int m0 = blockIdx.y << 7, n0 = blockIdx.x << 7;

    f32x4 acc[4][4] = {};
    const int l8 = (lane & 7) * 8;   // k-offset (elems) within chunk row
    const int lr = lane >> 3;        // row-in-chunk

    for (int k0 = 0; k0 < K; k0 += 64) {
        __syncthreads();
#pragma unroll
        for (int i = 0; i < 4; ++i) {
            int c = w * 4 + i;
            int row = c * 8 + lr;
            gload_lds16(A + (size_t)(m0 + row) * K + k0 + l8, (char*)As + c * 1024);
            gload_lds16(BT + (size_t)(n0 + row) * K + k0 + l8, (char*)Bs + c * 1024);
        }
        __syncthreads();
#pragma unroll
        for (int ks = 0; ks < 2; ++ks) {
            bf16x8 a[4], b[4];
#pragma unroll
            for (int i = 0; i < 4; ++i) {
                a[i] = *reinterpret_cast<const bf16x8*>(
                    As + (wr * 64 + i * 16 + (lane & 15)) * 64 + ks * 32 + (lane >> 4) * 8);
                b[i] = *reinterpret_cast<const bf16x8*>(
                    Bs + (wc * 64 + i * 16 + (lane & 15)) * 64 + ks * 32 + (lane >> 4) * 8);
            }
#pragma unroll
            for (int i = 0; i < 4; ++i)
#pragma unroll
                for (int j = 0; j < 4; ++j)
                    acc[i][j] = __builtin_amdgcn_mfma_f32_16x16x32_bf16(
                        a[i], b[j], acc[i][j], 0, 0, 0);
        }
    }

    const int col_l = lane & 15, rgrp = lane >> 4;
#pragma unroll
    for (int j = 0; j < 4; ++j) {
        int col = n0 + wc * 64 + j * 16 + col_l;
        float bv = bias[col];
#pragma unroll
        for (int i = 0; i < 4; ++i) {
            int rowb = m0 + wr * 64 + i * 16 + rgrp * 4;
#pragma unroll
            for (int r = 0; r < 4; ++r) {
                float v = acc[i][j][r] + bv;
                if (BF16_OUT)
                    ((__bf16*)Cout)[(size_t)(rowb + r) * N + col] = (__bf16)v;
                else
                    ((float*)Cout)[(size_t)(rowb + r) * N + col] = v;
            }
        }
    }
}

// ---------------------------------------------------------------------------
// Flash attention, bf16 MFMA. Block = (b, nh, q-tile of 128). 8 waves, each
// owns 16 q-rows. KV tile = 64 shared by all 8 waves. Q in regs; K/VT
// reg-staged into padded LDS; P via LDS; O accum fp32; epilogue transposes
// through an LDS overlay and writes T[b][nh*128+d][s] bf16.
// __launch_bounds__(512,2): VGPR cap 128 (steady-state ~110) -> no spill.
// ---------------------------------------------------------------------------
__global__ __launch_bounds__(512, 2) void mqa_attn_mfma(
    const __bf16* __restrict__ Q,   // [8192][2048]
    const __bf16* __restrict__ K,   // [8192][128]
    const __bf16* __restrict__ VT,  // [4][128][2048]
    __bf16* __restrict__ T)         // [4][2048][2048]
{
    // LDS plan (bf16 elems): Ks[64][136] @0 (8704) | Vt[128][72] @8704 (9216)
    //                        | Ps[8][16][72] @17920 (9216)  => 27136 elems, 54.3 KB
    // Epilogue overlays Eb[128][136] (17408 elems) at offset 0 after a barrier.
    __shared__ __bf16 smem[27136];
    __bf16 (*Ks)[136]     = reinterpret_cast<__bf16(*)[136]>(smem);
    __bf16 (*Vt)[72]      = reinterpret_cast<__bf16(*)[72]>(smem + 8704);
    __bf16 (*Ps)[16][72]  = reinterpret_cast<__bf16(*)[16][72]>(smem + 17920);

    const int t = threadIdx.x;
    const int lane = t & 63;
    const int w = t >> 6;            // 0..7
    const int bid = blockIdx.x;
    const int qb = bid & 15;         // 16 q-tiles of 128
    const int nh = (bid >> 4) & 15;
    const int b = bid >> 8;
    const int q0 = qb << 7;

    const int cl = lane & 15;        // col-in-frag / A-row
    const int rg = lane >> 4;        // k-group / C-row-group

    // Q fragments (held in registers for the whole kernel)
    bf16x8 qf[4];
    {
        const __bf16* qrow = Q + (size_t)(b * SLEN + q0 + w * 16 + cl) * HDIM
                             + nh * HD + rg * 8;
#pragma unroll
        for (int ks = 0; ks < 4; ++ks)
            qf[ks] = *reinterpret_cast<const bf16x8*>(qrow + ks * 32);
    }

    f32x4 O[8] = {};
    float m[4], l[4];
#pragma unroll
    for (int r = 0; r < 4; ++r) { m[r] = -__builtin_inff(); l[r] = 0.f; }

    const float scale = 0.08838834764831845f;  // 1/sqrt(128)

    // prefetch tile 0 into regs (K: 1024 float4, VT: 1024 float4; 2 each)
    float4 kd[2], vd[2];
    {
        const size_t kbase = (size_t)(b * SLEN) * HD;
#pragma unroll
        for (int i = 0; i < 2; ++i) {
            int id = i * 512 + t;
            int r = id >> 4, c = id & 15;
            kd[i] = *reinterpret_cast<const float4*>(K + kbase + (size_t)r * HD + c * 8);
        }
#pragma unroll
        for (int i = 0; i < 2; ++i) {
            int id = i * 512 + t;
            int r = id >> 3, c = id & 7;
            vd[i] = *reinterpret_cast<const float4*>(
                VT + (size_t)(b * HD + r) * SLEN + c * 8);
        }
    }

    for (int kk = 0; kk < SLEN; kk += 64) {
        __syncthreads();   // previous compute done reading Ks/Vt
        // commit staged regs to LDS
#pragma unroll
        for (int i = 0; i < 2; ++i) {
            int id = i * 512 + t;
            int r = id >> 4, c = id & 15;
            *reinterpret_cast<float4*>(&Ks[r][c * 8]) = kd[i];
        }
#pragma unroll
        for (int i = 0; i < 2; ++i) {
            int id = i * 512 + t;
            int r = id >> 3, c = id & 7;
            *reinterpret_cast<float4*>(&Vt[r][c * 8]) = vd[i];
        }
        __syncthreads();

        // prefetch next tile (overlaps with compute below)
        if (kk + 64 < SLEN) {
            const size_t kbase = (size_t)(b * SLEN + kk + 64) * HD;
#pragma unroll
            for (int i = 0; i < 2; ++i) {
                int id = i * 512 + t;
                int r = id >> 4, c = id & 15;
                kd[i] = *reinterpret_cast<const float4*>(K + kbase + (size_t)r * HD + c * 8);
            }
#pragma unroll
            for (int i = 0; i < 2; ++i) {
                int id = i * 512 + t;
                int r = id >> 3, c = id & 7;
                vd[i] = *reinterpret_cast<const float4*>(
                    VT + (size_t)(b * HD + r) * SLEN + kk + 64 + c * 8);
            }
        }

        // ---- S = Q K^T (per wave: 16 x 64) ----
        f32x4 s[4] = {};
#pragma unroll
        for (int cb = 0; cb < 4; ++cb)
#pragma unroll
            for (int ks = 0; ks < 4; ++ks) {
                bf16x8 kf = *reinterpret_cast<const bf16x8*>(
                    &Ks[cb * 16 + cl][ks * 32 + rg * 8]);
                s[cb] = __builtin_amdgcn_mfma_f32_16x16x32_bf16(qf[ks], kf, s[cb], 0, 0, 0);
            }

        // ---- online softmax ----
#pragma unroll
        for (int cb = 0; cb < 4; ++cb)
#pragma unroll
            for (int r = 0; r < 4; ++r) s[cb][r] *= scale;

        float rs[4];
#pragma unroll
        for (int r = 0; r < 4; ++r) {
            float tm = fmaxf(fmaxf(s[0][r], s[1][r]), fmaxf(s[2][r], s[3][r]));
            tm = fmaxf(tm, __shfl_xor(tm, 1));
            tm = fmaxf(tm, __shfl_xor(tm, 2));
            tm = fmaxf(tm, __shfl_xor(tm, 4));
            tm = fmaxf(tm, __shfl_xor(tm, 8));
            float mn = fmaxf(m[r], tm);
            float alpha = __expf(m[r] - mn);
            m[r] = mn;
            l[r] *= alpha;
#pragma unroll
            for (int dcb = 0; dcb < 8; ++dcb) O[dcb][r] *= alpha;
            rs[r] = 0.f;
        }
#pragma unroll
        for (int cb = 0; cb < 4; ++cb)
#pragma unroll
            for (int r = 0; r < 4; ++r) {
                float p = __expf(s[cb][r] - m[r]);
                rs[r] += p;
                Ps[w][rg * 4 + r][cb * 16 + cl] = (__bf16)p;
            }
#pragma unroll
        for (int r = 0; r < 4; ++r) {
            float v = rs[r];
            v += __shfl_xor(v, 1);
            v += __shfl_xor(v, 2);
            v += __shfl_xor(v, 4);
            v += __shfl_xor(v, 8);
            l[r] += v;
        }
        __syncthreads();   // P visible (and orders vs next staging)

        // ---- O += P @ V ----
        bf16x8 pf[2];
#pragma unroll
        for (int ks = 0; ks < 2; ++ks)
            pf[ks] = *reinterpret_cast<const bf16x8*>(&Ps[w][cl][ks * 32 + rg * 8]);
#pragma unroll
        for (int dcb = 0; dcb < 8; ++dcb)
#pragma unroll
            for (int ks = 0; ks < 2; ++ks) {
                bf16x8 vf = *reinterpret_cast<const bf16x8*>(
                    &Vt[dcb * 16 + cl][ks * 32 + rg * 8]);
                O[dcb] = __builtin_amdgcn_mfma_f32_16x16x32_bf16(pf[ks], vf, O[dcb], 0, 0, 0);
            }
    }

    // ---- epilogue: normalize, transpose via LDS overlay, write T ----
    __syncthreads();   // all waves done reading Ks/Vt before overlay
    __bf16 (*Eb)[136] = reinterpret_cast<__bf16(*)[136]>(smem);
    float invl[4];
#pragma unroll
    for (int r = 0; r < 4; ++r) invl[r] = 1.0f / l[r];
    // O[dcb][r] holds: q-row = rg*4+r (within wave), d-col = dcb*16+cl
#pragma unroll
    for (int dcb = 0; dcb < 8; ++dcb)
#pragma unroll
        for (int r = 0; r < 4; ++r)
            Eb[dcb * 16 + cl][w * 16 + rg * 4 + r] = (__bf16)(O[dcb][r] * invl[r]);
    __syncthreads();
    // write [128 d][128 s] tile: 2048 float4, 4 per thread
#pragma unroll
    for (int i = 0; i < 4; ++i) {
        int id = i * 512 + t;
        int d = id >> 4, c = id & 15;
        float4 v = *reinterpret_cast<const float4*>(&Eb[d][c * 8]);
        *reinterpret_cast<float4*>(
            T + (size_t)(b * HDIM + nh * HD + d) * SLEN + q0 + c * 8) = v;
    }
}

// ---------------------------------------------------------------------------
extern "C" void kernel_launch(void* const* d_in, const int* in_sizes, int n_in,
                              void* d_out, int out_size, void* d_ws, size_t ws_size,
                              hipStream_t stream) {
    const float* hs  = (const float*)d_in[0];
    const float* w_q = (const float*)d_in[1];
    const float* b_q = (const float*)d_in[2];
    const float* w_k = (const float*)d_in[3];
    const float* b_k = (const float*)d_in[4];
    const float* w_v = (const float*)d_in[5];
    const float* b_v = (const float*)d_in[6];
    const float* w_o = (const float*)d_in[7];
    const float* b_o = (const float*)d_in[8];

    const int M = BATCH * SLEN;          // 8192
    const size_t MH = (size_t)M * HDIM;  // 16.8M

    // d_out (67.1 MB) partition: [hs_bf16 33.55MB][Q 33.55MB]
    __bf16* hs_b = (__bf16*)d_out;
    __bf16* Qb   = hs_b + MH;

    // ws partition (57.7 MB total)
    char* p = (char*)d_ws;
    __bf16* wqT = (__bf16*)p;             p += (size_t)HDIM * HDIM * 2;  // 8.39MB
    __bf16* woT = (__bf16*)p;             p += (size_t)HDIM * HDIM * 2;  // 8.39MB
    __bf16* wkT = (__bf16*)p;             p += (size_t)HD * HDIM * 2;    // 0.52MB
    __bf16* wvT = (__bf16*)p;             p += (size_t)HD * HDIM * 2;    // 0.52MB
    __bf16* Kb  = (__bf16*)p;             p += (size_t)M * HD * 2;       // 2.10MB
    __bf16* Vb  = (__bf16*)p;             p += (size_t)M * HD * 2;       // 2.10MB
    __bf16* VTb = (__bf16*)p;             p += (size_t)M * HD * 2;       // 2.10MB
    __bf16* Tb  = (__bf16*)p;                                            // 33.55MB

    dim3 blk(256);

    // converts
    conv_bf16<<<dim3(MH / (256 * 8)), blk, 0, stream>>>(hs, hs_b);
    transpose_conv<<<dim3(HDIM / 32, HDIM / 32), blk, 0, stream>>>(w_q, wqT, HDIM, HDIM);
    transpose_conv<<<dim3(HD / 32, HDIM / 32), blk, 0, stream>>>(w_k, wkT, HDIM, HD);
    transpose_conv<<<dim3(HD / 32, HDIM / 32), blk, 0, stream>>>(w_v, wvT, HDIM, HD);
    transpose_conv<<<dim3(HDIM / 32, HDIM / 32), blk, 0, stream>>>(w_o, woT, HDIM, HDIM);

    // projections
    gemm_bt<true><<<dim3(HDIM / 128, M / 128), blk, 0, stream>>>(
        hs_b, wqT, b_q, Qb, M, HDIM, HDIM);
    gemm_bt<true><<<dim3(HD / 128, M / 128), blk, 0, stream>>>(
        hs_b, wkT, b_k, Kb, M, HD, HDIM);
    gemm_bt<true><<<dim3(HD / 128, M / 128), blk, 0, stream>>>(
        hs_b, wvT, b_v, Vb, M, HD, HDIM);
    transpose_v<<<dim3(HD / 32, SLEN / 32, BATCH), blk, 0, stream>>>(Vb, VTb);

    // attention (QBLK=128, 8 waves)
    mqa_attn_mfma<<<dim3(BATCH * NHEADS * (SLEN / 128)), dim3(512), 0, stream>>>(
        Qb, Kb, VTb, Tb);

    // output projection (contracts over seq via T layout)
    gemm_bt<false><<<dim3(HDIM / 128, M / 128), blk, 0, stream>>>(
        Tb, woT, b_o, d_out, M, HDIM, HDIM);
}

// Round 9
// 702.156 us; speedup vs baseline: 7.1677x; 1.0880x over previous
//
#include <hip/hip_runtime.h>
#include <math.h>

// MQA bf16-MFMA pipeline. B=4, S=2048, H=2048, NH=16, HD=128.
//  conv:  hs f32 -> hs_bf16 (d_out lo half)
//  convT: w_q/w_k/w_v/w_o f32 [K][N] -> bf16 [N][K] (ws)
//  P1: Q = hs @ w_q + b_q   bf16 -> d_out hi half
//  P2: K = hs @ w_k + b_k   bf16 -> ws
//  P3: V = hs @ w_v + b_v   written TRANSPOSED -> VT[b][d][s] (ws)
//  P4: flash attn (MFMA, QBLK=128, 8 waves, gload_lds+XOR-swizzled LDS)
//      -> T[b][nh*128+d][s] bf16 (ws)
//  P5: out = T @ w_o + b_o  f32 -> d_out

#define BATCH 4
#define SLEN 2048
#define HDIM 2048
#define NHEADS 16
#define HD 128

typedef __bf16 bf16x8 __attribute__((ext_vector_type(8)));
typedef float f32x4 __attribute__((ext_vector_type(4)));

__device__ __forceinline__ void gload_lds16(const void* g, void* l) {
    __builtin_amdgcn_global_load_lds(
        (const __attribute__((address_space(1))) void*)g,
        (__attribute__((address_space(3))) void*)l, 16, 0, 0);
}

// bijective XCD-chunked swizzle; requires nwg % 8 == 0
__device__ __forceinline__ int xcd_swizzle(int bid, int nwg) {
    int cpx = nwg >> 3;
    return (bid & 7) * cpx + (bid >> 3);
}

// ---------------------------------------------------------------------------
// conv: f32 -> bf16, 8 elems/thread
// ---------------------------------------------------------------------------
__global__ void conv_bf16(const float* __restrict__ in, __bf16* __restrict__ out) {
    int i = (blockIdx.x * 256 + threadIdx.x) * 8;
    float4 a = *reinterpret_cast<const float4*>(in + i);
    float4 b = *reinterpret_cast<const float4*>(in + i + 4);
    bf16x8 o;
    o[0] = (__bf16)a.x; o[1] = (__bf16)a.y; o[2] = (__bf16)a.z; o[3] = (__bf16)a.w;
    o[4] = (__bf16)b.x; o[5] = (__bf16)b.y; o[6] = (__bf16)b.z; o[7] = (__bf16)b.w;
    *reinterpret_cast<bf16x8*>(out + i) = o;
}

// ---------------------------------------------------------------------------
// transpose+convert: in f32 [R][C] -> out bf16 [C][R]
// ---------------------------------------------------------------------------
__global__ void transpose_conv(const float* __restrict__ in, __bf16* __restrict__ out,
                               int R, int C) {
    __shared__ float tile[32][33];
    int c0 = blockIdx.x * 32, r0 = blockIdx.y * 32;
    int tr = threadIdx.x >> 5, tc = threadIdx.x & 31;
#pragma unroll
    for (int i = 0; i < 4; ++i)
        tile[tr + i * 8][tc] = in[(size_t)(r0 + tr + i * 8) * C + c0 + tc];
    __syncthreads();
#pragma unroll
    for (int i = 0; i < 4; ++i)
        out[(size_t)(c0 + tr + i * 8) * R + r0 + tc] = (__bf16)tile[tc][tr + i * 8];
}

// ---------------------------------------------------------------------------
// bf16 GEMM (m97 structure): C[M][N] = A[M][K] @ BT[N][K]^T + bias
// 128x128 tile, BK=64, 4 waves (2x2). 1D grid + XCD swizzle.
// MODE: 0 = f32 out, 1 = bf16 out, 2 = bf16 out transposed to VT[b][d][s]
// ---------------------------------------------------------------------------
template <int MODE>
__global__ __launch_bounds__(256) void gemm_bt(
    const __bf16* __restrict__ A, const __bf16* __restrict__ BT,
    const float* __restrict__ bias, void* __restrict__ Cout,
    int M, int N, int K, int nbx)
{
    __shared__ __bf16 As[128 * 64];
    __shared__ __bf16 Bs[128 * 64];
    const int t = threadIdx.x;
    const int lane = t & 63;
    const int w = t >> 6;
    const int wr = w >> 1, wc = w & 1;
    const int id = xcd_swizzle(blockIdx.x, gridDim.x);
    const int m0 = (id / nbx) << 7, n0 = (id % nbx) << 7;

    f32x4 acc[4][4] = {};
    const int l8 = (lane & 7) * 8;   // k-offset (elems) within chunk row
    const int lr = lane >> 3;        // row-in-chunk

    for (int k0 = 0; k0 < K; k0 += 64) {
        __syncthreads();
#pragma unroll
        for (int i = 0; i < 4; ++i) {
            int c = w * 4 + i;
            int row = c * 8 + lr;
            gload_lds16(A + (size_t)(m0 + row) * K + k0 + l8, (char*)As + c * 1024);
            gload_lds16(BT + (size_t)(n0 + row) * K + k0 + l8, (char*)Bs + c * 1024);
        }
        __syncthreads();
#pragma unroll
        for (int ks = 0; ks < 2; ++ks) {
            bf16x8 a[4], b[4];
#pragma unroll
            for (int i = 0; i < 4; ++i) {
                a[i] = *reinterpret_cast<const bf16x8*>(
                    As + (wr * 64 + i * 16 + (lane & 15)) * 64 + ks * 32 + (lane >> 4) * 8);
                b[i] = *reinterpret_cast<const bf16x8*>(
                    Bs + (wc * 64 + i * 16 + (lane & 15)) * 64 + ks * 32 + (lane >> 4) * 8);
            }
#pragma unroll
            for (int i = 0; i < 4; ++i)
#pragma unroll
                for (int j = 0; j < 4; ++j)
                    acc[i][j] = __builtin_amdgcn_mfma_f32_16x16x32_bf16(
                        a[i], b[j], acc[i][j], 0, 0, 0);
        }
    }

    const int col_l = lane & 15, rgrp = lane >> 4;
#pragma unroll
    for (int j = 0; j < 4; ++j) {
        int col = n0 + wc * 64 + j * 16 + col_l;
        float bv = bias[col];
#pragma unroll
        for (int i = 0; i < 4; ++i) {
            int rowb = m0 + wr * 64 + i * 16 + rgrp * 4;
#pragma unroll
            for (int r = 0; r < 4; ++r) {
                float v = acc[i][j][r] + bv;
                int row = rowb + r;
                if (MODE == 0)
                    ((float*)Cout)[(size_t)row * N + col] = v;
                else if (MODE == 1)
                    ((__bf16*)Cout)[(size_t)row * N + col] = (__bf16)v;
                else  // MODE 2: VT[b][col][s], row = b*SLEN + s
                    ((__bf16*)Cout)[((size_t)(row >> 11) * HD + col) * SLEN
                                    + (row & (SLEN - 1))] = (__bf16)v;
            }
        }
    }
}

// ---------------------------------------------------------------------------
// Flash attention, bf16 MFMA. Block = (b, nh, q-tile of 128). 8 waves, each
// owns 16 q-rows. KV tile = 64. Q in regs. K/VT staged via global_load_lds
// into LINEAR LDS with pre-swizzled global source (chunk ^= row&7); reads
// apply the same XOR -> bank-conflict-free without padding and no staging
// VGPRs. Ps via LDS (per-wave). O accum fp32. Epilogue transposes through
// an LDS overlay and writes T[b][nh*128+d][s] bf16.
// ---------------------------------------------------------------------------
__attribute__((amdgpu_waves_per_eu(2, 4)))
__global__ __launch_bounds__(512) void mqa_attn_mfma(
    const __bf16* __restrict__ Q,   // [8192][2048]
    const __bf16* __restrict__ K,   // [8192][128]
    const __bf16* __restrict__ VT,  // [4][128][2048]
    __bf16* __restrict__ T)         // [4][2048][2048]
{
    // LDS (bf16 elems): Ks_lin 64x128 @0 (8192) | Vt_lin 128x64 @8192 (8192)
    //                   | Ps[8][16][72] @16384 (9216) => 25600 elems, 51.2 KB
    // Epilogue overlays Eb[128][136] (17408 elems) at 0 after a barrier.
    __shared__ __align__(16) __bf16 smem[25600];
    __bf16* KsB = smem;           // row stride 128 elems (256B), chunk=16B
    __bf16* VtB = smem + 8192;    // row stride 64 elems (128B)
    __bf16 (*Ps)[16][72] = reinterpret_cast<__bf16(*)[16][72]>(smem + 16384);

    const int t = threadIdx.x;
    const int lane = t & 63;
    const int w = t >> 6;            // 0..7
    const int bid = xcd_swizzle(blockIdx.x, gridDim.x);
    const int qb = bid & 15;         // 16 q-tiles of 128
    const int nh = (bid >> 4) & 15;
    const int b = bid >> 8;
    const int q0 = qb << 7;

    const int cl = lane & 15;        // col-in-frag / A-row
    const int rg = lane >> 4;        // k-group / C-row-group

    // Q fragments (held in registers for the whole kernel)
    bf16x8 qf[4];
    {
        const __bf16* qrow = Q + (size_t)(b * SLEN + q0 + w * 16 + cl) * HDIM
                             + nh * HD + rg * 8;
#pragma unroll
        for (int ks = 0; ks < 4; ++ks)
            qf[ks] = *reinterpret_cast<const bf16x8*>(qrow + ks * 32);
    }

    f32x4 O[8] = {};
    float m[4], l[4];
#pragma unroll
    for (int r = 0; r < 4; ++r) { m[r] = -__builtin_inff(); l[r] = 0.f; }

    const float scale = 0.08838834764831845f;  // 1/sqrt(128)

    // per-lane swizzled staging geometry (constant across iters)
    const int k_row0 = (w * 2) * 4 + (lane >> 4);      // j adds 4
    const int k_cc0  = lane & 15;
    const int v_row0 = (w * 2) * 8 + (lane >> 3);      // j adds 8
    const int v_cc0  = lane & 7;

    for (int kk = 0; kk < SLEN; kk += 64) {
        __syncthreads();   // all waves done reading Ks/Vt (and prior Ps)
        // stage K tile [64][128] and V tile [128][64] via DMA, swizzled source
#pragma unroll
        for (int j = 0; j < 2; ++j) {
            int idx = w * 2 + j;
            int row = k_row0 + j * 4;
            int cc  = k_cc0 ^ (row & 7);
            gload_lds16(K + (size_t)(b * SLEN + kk + row) * HD + cc * 8,
                        (char*)KsB + idx * 1024);
        }
#pragma unroll
        for (int j = 0; j < 2; ++j) {
            int idx = w * 2 + j;
            int row = v_row0 + j * 8;
            int cc  = v_cc0 ^ (row & 7);
            gload_lds16(VT + (size_t)(b * HD + row) * SLEN + kk + cc * 8,
                        (char*)VtB + idx * 1024);
        }
        __syncthreads();   // DMA drained (syncthreads waits vmcnt 0)

        // ---- S = Q K^T (per wave: 16 x 64) ----
        f32x4 s[4] = {};
#pragma unroll
        for (int cb = 0; cb < 4; ++cb) {
            const int row = cb * 16 + cl;
            const __bf16* kr = KsB + row * 128;
            const int sw = row & 7;
#pragma unroll
            for (int ks = 0; ks < 4; ++ks) {
                bf16x8 kf = *reinterpret_cast<const bf16x8*>(
                    kr + (((ks * 4 + rg) ^ sw) << 3));
                s[cb] = __builtin_amdgcn_mfma_f32_16x16x32_bf16(qf[ks], kf, s[cb], 0, 0, 0);
            }
        }

        // ---- online softmax ----
#pragma unroll
        for (int cb = 0; cb < 4; ++cb)
#pragma unroll
            for (int r = 0; r < 4; ++r) s[cb][r] *= scale;

        float rs[4];
#pragma unroll
        for (int r = 0; r < 4; ++r) {
            float tm = fmaxf(fmaxf(s[0][r], s[1][r]), fmaxf(s[2][r], s[3][r]));
            tm = fmaxf(tm, __shfl_xor(tm, 1));
            tm = fmaxf(tm, __shfl_xor(tm, 2));
            tm = fmaxf(tm, __shfl_xor(tm, 4));
            tm = fmaxf(tm, __shfl_xor(tm, 8));
            float mn = fmaxf(m[r], tm);
            float alpha = __expf(m[r] - mn);
            m[r] = mn;
            l[r] *= alpha;
#pragma unroll
            for (int dcb = 0; dcb < 8; ++dcb) O[dcb][r] *= alpha;
            rs[r] = 0.f;
        }
#pragma unroll
        for (int cb = 0; cb < 4; ++cb)
#pragma unroll
            for (int r = 0; r < 4; ++r) {
                float p = __expf(s[cb][r] - m[r]);
                rs[r] += p;
                Ps[w][rg * 4 + r][cb * 16 + cl] = (__bf16)p;
            }
#pragma unroll
        for (int r = 0; r < 4; ++r) {
            float v = rs[r];
            v += __shfl_xor(v, 1);
            v += __shfl_xor(v, 2);
            v += __shfl_xor(v, 4);
            v += __shfl_xor(v, 8);
            l[r] += v;
        }
        // Ps is per-wave: same-wave ds write->read ordering handled by
        // compiler-inserted lgkmcnt waits; no block barrier needed here.

        // ---- O += P @ V ----
        bf16x8 pf[2];
#pragma unroll
        for (int ks = 0; ks < 2; ++ks)
            pf[ks] = *reinterpret_cast<const bf16x8*>(&Ps[w][cl][ks * 32 + rg * 8]);
#pragma unroll
        for (int dcb = 0; dcb < 8; ++dcb) {
            const int row = dcb * 16 + cl;
            const __bf16* vr = VtB + row * 64;
            const int sw = row & 7;
#pragma unroll
            for (int ks = 0; ks < 2; ++ks) {
                bf16x8 vf = *reinterpret_cast<const bf16x8*>(
                    vr + (((ks * 4 + rg) ^ sw) << 3));
                O[dcb] = __builtin_amdgcn_mfma_f32_16x16x32_bf16(pf[ks], vf, O[dcb], 0, 0, 0);
            }
        }
    }

    // ---- epilogue: normalize, transpose via LDS overlay, write T ----
    __syncthreads();   // all waves done with Ks/Vt/Ps before overlay
    __bf16 (*Eb)[136] = reinterpret_cast<__bf16(*)[136]>(smem);
    float invl[4];
#pragma unroll
    for (int r = 0; r < 4; ++r) invl[r] = 1.0f / l[r];
    // O[dcb][r]: q-row = w*16 + rg*4 + r, d-col = dcb*16 + cl
#pragma unroll
    for (int dcb = 0; dcb < 8; ++dcb)
#pragma unroll
        for (int r = 0; r < 4; ++r)
            Eb[dcb * 16 + cl][w * 16 + rg * 4 + r] = (__bf16)(O[dcb][r] * invl[r]);
    __syncthreads();
    // write [128 d][128 s] tile: 2048 float4, 4 per thread
#pragma unroll
    for (int i = 0; i < 4; ++i) {
        int id = i * 512 + t;
        int d = id >> 4, c = id & 15;
        float4 v = *reinterpret_cast<const float4*>(&Eb[d][c * 8]);
        *reinterpret_cast<float4*>(
            T + (size_t)(b * HDIM + nh * HD + d) * SLEN + q0 + c * 8) = v;
    }
}

// ---------------------------------------------------------------------------
extern "C" void kernel_launch(void* const* d_in, const int* in_sizes, int n_in,
                              void* d_out, int out_size, void* d_ws, size_t ws_size,
                              hipStream_t stream) {
    const float* hs  = (const float*)d_in[0];
    const float* w_q = (const float*)d_in[1];
    const float* b_q = (const float*)d_in[2];
    const float* w_k = (const float*)d_in[3];
    const float* b_k = (const float*)d_in[4];
    const float* w_v = (const float*)d_in[5];
    const float* b_v = (const float*)d_in[6];
    const float* w_o = (const float*)d_in[7];
    const float* b_o = (const float*)d_in[8];

    const int M = BATCH * SLEN;          // 8192
    const size_t MH = (size_t)M * HDIM;  // 16.8M

    // d_out (67.1 MB) partition: [hs_bf16 33.55MB][Q 33.55MB]
    __bf16* hs_b = (__bf16*)d_out;
    __bf16* Qb   = hs_b + MH;

    // ws partition
    char* p = (char*)d_ws;
    __bf16* wqT = (__bf16*)p;             p += (size_t)HDIM * HDIM * 2;  // 8.39MB
    __bf16* woT = (__bf16*)p;             p += (size_t)HDIM * HDIM * 2;  // 8.39MB
    __bf16* wkT = (__bf16*)p;             p += (size_t)HD * HDIM * 2;    // 0.52MB
    __bf16* wvT = (__bf16*)p;             p += (size_t)HD * HDIM * 2;    // 0.52MB
    __bf16* Kb  = (__bf16*)p;             p += (size_t)M * HD * 2;       // 2.10MB
    __bf16* VTb = (__bf16*)p;             p += (size_t)M * HD * 2;       // 2.10MB
    __bf16* Tb  = (__bf16*)p;                                            // 33.55MB

    dim3 blk(256);

    // converts
    conv_bf16<<<dim3(MH / (256 * 8)), blk, 0, stream>>>(hs, hs_b);
    transpose_conv<<<dim3(HDIM / 32, HDIM / 32), blk, 0, stream>>>(w_q, wqT, HDIM, HDIM);
    transpose_conv<<<dim3(HD / 32, HDIM / 32), blk, 0, stream>>>(w_k, wkT, HDIM, HD);
    transpose_conv<<<dim3(HD / 32, HDIM / 32), blk, 0, stream>>>(w_v, wvT, HDIM, HD);
    transpose_conv<<<dim3(HDIM / 32, HDIM / 32), blk, 0, stream>>>(w_o, woT, HDIM, HDIM);

    // projections (1D grids, XCD-swizzled)
    gemm_bt<1><<<dim3(16 * (M / 128)), blk, 0, stream>>>(
        hs_b, wqT, b_q, Qb, M, HDIM, HDIM, 16);
    gemm_bt<1><<<dim3(1 * (M / 128)), blk, 0, stream>>>(
        hs_b, wkT, b_k, Kb, M, HD, HDIM, 1);
    gemm_bt<2><<<dim3(1 * (M / 128)), blk, 0, stream>>>(
        hs_b, wvT, b_v, VTb, M, HD, HDIM, 1);   // writes VT[b][d][s] directly

    // attention (QBLK=128, 8 waves)
    mqa_attn_mfma<<<dim3(BATCH * NHEADS * (SLEN / 128)), dim3(512), 0, stream>>>(
        Qb, Kb, VTb, Tb);

    // output projection (contracts over seq via T layout)
    gemm_bt<0><<<dim3(16 * (M / 128)), blk, 0, stream>>>(
        Tb, woT, b_o, d_out, M, HDIM, HDIM, 16);
}

// Round 11
// 644.016 us; speedup vs baseline: 7.8148x; 1.0903x over previous
//
#include <hip/hip_runtime.h>
#include <math.h>

// MQA bf16-MFMA pipeline. B=4, S=2048, H=2048, NH=16, HD=128.
//  conv:  hs f32 -> hs_bf16 (d_out lo half)
//  convT: w_q/w_k/w_v/w_o f32 [K][N] -> bf16 [N][K] (ws)
//  P1: Q = hs @ w_q + b_q   bf16 -> d_out hi half
//  P2: fused KV proj (MODE 3): K -> ws, V written transposed -> VT[b][d][s]
//  P4: flash attn (MFMA, QBLK=128, 8 waves, dbuf K/V, 1 barrier/iter,
//      defer-max, setprio) -> T[b][nh*128+d][s] bf16 (ws)
//  P5: out = T @ w_o + b_o  f32 -> d_out

#define BATCH 4
#define SLEN 2048
#define HDIM 2048
#define NHEADS 16
#define HD 128

typedef __bf16 bf16x8 __attribute__((ext_vector_type(8)));
typedef float f32x4 __attribute__((ext_vector_type(4)));

__device__ __forceinline__ void gload_lds16(const void* g, void* l) {
    __builtin_amdgcn_global_load_lds(
        (const __attribute__((address_space(1))) void*)g,
        (__attribute__((address_space(3))) void*)l, 16, 0, 0);
}

// bijective XCD-chunked swizzle; requires nwg % 8 == 0
__device__ __forceinline__ int xcd_swizzle(int bid, int nwg) {
    int cpx = nwg >> 3;
    return (bid & 7) * cpx + (bid >> 3);
}

// ---------------------------------------------------------------------------
// conv: f32 -> bf16, 8 elems/thread
// ---------------------------------------------------------------------------
__global__ void conv_bf16(const float* __restrict__ in, __bf16* __restrict__ out) {
    int i = (blockIdx.x * 256 + threadIdx.x) * 8;
    float4 a = *reinterpret_cast<const float4*>(in + i);
    float4 b = *reinterpret_cast<const float4*>(in + i + 4);
    bf16x8 o;
    o[0] = (__bf16)a.x; o[1] = (__bf16)a.y; o[2] = (__bf16)a.z; o[3] = (__bf16)a.w;
    o[4] = (__bf16)b.x; o[5] = (__bf16)b.y; o[6] = (__bf16)b.z; o[7] = (__bf16)b.w;
    *reinterpret_cast<bf16x8*>(out + i) = o;
}

// ---------------------------------------------------------------------------
// transpose+convert: in f32 [R][C] -> out bf16 [C][R]
// ---------------------------------------------------------------------------
__global__ void transpose_conv(const float* __restrict__ in, __bf16* __restrict__ out,
                               int R, int C) {
    __shared__ float tile[32][33];
    int c0 = blockIdx.x * 32, r0 = blockIdx.y * 32;
    int tr = threadIdx.x >> 5, tc = threadIdx.x & 31;
#pragma unroll
    for (int i = 0; i < 4; ++i)
        tile[tr + i * 8][tc] = in[(size_t)(r0 + tr + i * 8) * C + c0 + tc];
    __syncthreads();
#pragma unroll
    for (int i = 0; i < 4; ++i)
        out[(size_t)(c0 + tr + i * 8) * R + r0 + tc] = (__bf16)tile[tc][tr + i * 8];
}

// ---------------------------------------------------------------------------
// bf16 GEMM (m97 structure): C[M][N] = A[M][K] @ BT[N][K]^T + bias
// 128x128 tile, BK=64, 4 waves (2x2). 1D grid + XCD swizzle.
// MODE: 0 = f32 out, 1 = bf16 out,
//       3 = fused KV: col<HD -> K[row][col] (bias), col>=HD -> VT[b][col-HD][s] (bias2)
// ---------------------------------------------------------------------------
template <int MODE>
__global__ __launch_bounds__(256) void gemm_bt(
    const __bf16* __restrict__ A, const __bf16* __restrict__ BT,
    const float* __restrict__ bias, const float* __restrict__ bias2,
    void* __restrict__ Cout, void* __restrict__ Cout2,
    int M, int N, int K, int nbx)
{
    __shared__ __bf16 As[128 * 64];
    __shared__ __bf16 Bs[128 * 64];
    const int t = threadIdx.x;
    const int lane = t & 63;
    const int w = t >> 6;
    const int wr = w >> 1, wc = w & 1;
    const int id = xcd_swizzle(blockIdx.x, gridDim.x);
    const int m0 = (id / nbx) << 7, n0 = (id % nbx) << 7;

    f32x4 acc[4][4] = {};
    const int l8 = (lane & 7) * 8;   // k-offset (elems) within chunk row
    const int lr = lane >> 3;        // row-in-chunk

    for (int k0 = 0; k0 < K; k0 += 64) {
        __syncthreads();
#pragma unroll
        for (int i = 0; i < 4; ++i) {
            int c = w * 4 + i;
            int row = c * 8 + lr;
            gload_lds16(A + (size_t)(m0 + row) * K + k0 + l8, (char*)As + c * 1024);
            gload_lds16(BT + (size_t)(n0 + row) * K + k0 + l8, (char*)Bs + c * 1024);
        }
        __syncthreads();
#pragma unroll
        for (int ks = 0; ks < 2; ++ks) {
            bf16x8 a[4], b[4];
#pragma unroll
            for (int i = 0; i < 4; ++i) {
                a[i] = *reinterpret_cast<const bf16x8*>(
                    As + (wr * 64 + i * 16 + (lane & 15)) * 64 + ks * 32 + (lane >> 4) * 8);
                b[i] = *reinterpret_cast<const bf16x8*>(
                    Bs + (wc * 64 + i * 16 + (lane & 15)) * 64 + ks * 32 + (lane >> 4) * 8);
            }
#pragma unroll
            for (int i = 0; i < 4; ++i)
#pragma unroll
                for (int j = 0; j < 4; ++j)
                    acc[i][j] = __builtin_amdgcn_mfma_f32_16x16x32_bf16(
                        a[i], b[j], acc[i][j], 0, 0, 0);
        }
    }

    const int col_l = lane & 15, rgrp = lane >> 4;
#pragma unroll
    for (int j = 0; j < 4; ++j) {
        int col = n0 + wc * 64 + j * 16 + col_l;
        float bv;
        if (MODE == 3)
            bv = (col < HD) ? bias[col] : bias2[col - HD];
        else
            bv = bias[col];
#pragma unroll
        for (int i = 0; i < 4; ++i) {
            int rowb = m0 + wr * 64 + i * 16 + rgrp * 4;
#pragma unroll
            for (int r = 0; r < 4; ++r) {
                float v = acc[i][j][r] + bv;
                int row = rowb + r;
                if (MODE == 0)
                    ((float*)Cout)[(size_t)row * N + col] = v;
                else if (MODE == 1)
                    ((__bf16*)Cout)[(size_t)row * N + col] = (__bf16)v;
                else {  // MODE 3
                    if (col < HD)
                        ((__bf16*)Cout)[(size_t)row * HD + col] = (__bf16)v;
                    else
                        ((__bf16*)Cout2)[((size_t)(row >> 11) * HD + (col - HD)) * SLEN
                                         + (row & (SLEN - 1))] = (__bf16)v;
                }
            }
        }
    }
}

// ---------------------------------------------------------------------------
// Flash attention, bf16 MFMA. Block = (b, nh, q-tile of 128). 8 waves, each
// owns 16 q-rows. KV tile = 64, DOUBLE-BUFFERED: tile t+1's global_load_lds
// DMA is issued before computing tile t; the single end-of-iter barrier
// drains it after a full compute phase of overlap. Pre-swizzled source +
// XOR reads (bank-conflict-free, no staging VGPRs). Softmax: scale folded
// into Q, defer-max (THR=8) skips the O-rescale when the running max holds.
// LDS = exactly 80 KB -> 2 blocks/CU.
// ---------------------------------------------------------------------------
__attribute__((amdgpu_waves_per_eu(2, 4)))
__global__ __launch_bounds__(512) void mqa_attn_mfma(
    const __bf16* __restrict__ Q,   // [8192][2048]
    const __bf16* __restrict__ K,   // [8192][128]
    const __bf16* __restrict__ VT,  // [4][128][2048]
    __bf16* __restrict__ T)         // [4][2048][2048]
{
    // LDS (bf16 elems): K bufs 2x8192 @0 | V bufs 2x8192 @16384
    //                   | Ps 8x16x64 @32768  => 40960 elems = 80 KB exactly.
    // Epilogue overlays Eb[128][136] (34.8 KB) at 0 after the final barrier.
    __shared__ __align__(16) __bf16 smem[40960];
    __bf16* KsB = smem;            // per-buf 8192 elems; row stride 128
    __bf16* VtB = smem + 16384;    // per-buf 8192 elems; row stride 64
    __bf16* PsB = smem + 32768;    // per-wave 1024 elems; row stride 64, XOR-chunk

    const int t = threadIdx.x;
    const int lane = t & 63;
    const int w = t >> 6;            // 0..7
    const int bid = xcd_swizzle(blockIdx.x, gridDim.x);
    const int qb = bid & 15;         // 16 q-tiles of 128
    const int nh = (bid >> 4) & 15;
    const int b = bid >> 8;
    const int q0 = qb << 7;

    const int cl = lane & 15;        // col-in-frag / A-row
    const int rg = lane >> 4;        // k-group / C-row-group

    const float scale = 0.08838834764831845f;  // 1/sqrt(128)

    // Q fragments, scale pre-folded (kills the per-iter s*=scale pass)
    bf16x8 qf[4];
    {
        const __bf16* qrow = Q + (size_t)(b * SLEN + q0 + w * 16 + cl) * HDIM
                             + nh * HD + rg * 8;
#pragma unroll
        for (int ks = 0; ks < 4; ++ks) {
            bf16x8 raw = *reinterpret_cast<const bf16x8*>(qrow + ks * 32);
#pragma unroll
            for (int j = 0; j < 8; ++j)
                qf[ks][j] = (__bf16)((float)raw[j] * scale);
        }
    }

    f32x4 O[8] = {};
    float m[4], l[4];
#pragma unroll
    for (int r = 0; r < 4; ++r) { m[r] = -__builtin_inff(); l[r] = 0.f; }

    // per-lane swizzled staging geometry (constant across iters)
    const int k_row0 = (w * 2) * 4 + (lane >> 4);      // j adds 4
    const int k_cc0  = lane & 15;
    const int v_row0 = (w * 2) * 8 + (lane >> 3);      // j adds 8
    const int v_cc0  = lane & 7;

#define STAGE_KV(TILE, BUF)                                                     \
    do {                                                                        \
        int kk_ = (TILE) * 64;                                                  \
        _Pragma("unroll")                                                       \
        for (int j = 0; j < 2; ++j) {                                           \
            int idx = w * 2 + j;                                                \
            int row = k_row0 + j * 4;                                           \
            int cc  = k_cc0 ^ (row & 7);                                        \
            gload_lds16(K + (size_t)(b * SLEN + kk_ + row) * HD + cc * 8,       \
                        (char*)(KsB + (BUF) * 8192) + idx * 1024);              \
        }                                                                       \
        _Pragma("unroll")                                                       \
        for (int j = 0; j < 2; ++j) {                                           \
            int idx = w * 2 + j;                                                \
            int row = v_row0 + j * 8;                                           \
            int cc  = v_cc0 ^ (row & 7);                                        \
            gload_lds16(VT + (size_t)(b * HD + row) * SLEN + kk_ + cc * 8,      \
                        (char*)(VtB + (BUF) * 8192) + idx * 1024);              \
        }                                                                       \
    } while (0)

    // prologue: stage tile 0
    STAGE_KV(0, 0);
    __syncthreads();

    int buf = 0;
    const int NT = SLEN / 64;  // 32
    for (int tt = 0; tt < NT; ++tt) {
        // issue next tile's DMA into the other buffer (overlaps compute below)
        if (tt + 1 < NT) STAGE_KV(tt + 1, buf ^ 1);

        const __bf16* Kb_ = KsB + buf * 8192;
        const __bf16* Vb_ = VtB + buf * 8192;

        // ---- S = (Q*scale) K^T (per wave: 16 x 64) ----
        f32x4 s[4] = {};
        __builtin_amdgcn_s_setprio(1);
#pragma unroll
        for (int cb = 0; cb < 4; ++cb) {
            const int row = cb * 16 + cl;
            const __bf16* kr = Kb_ + row * 128;
            const int sw = row & 7;
#pragma unroll
            for (int ks = 0; ks < 4; ++ks) {
                bf16x8 kf = *reinterpret_cast<const bf16x8*>(
                    kr + (((ks * 4 + rg) ^ sw) << 3));
                s[cb] = __builtin_amdgcn_mfma_f32_16x16x32_bf16(qf[ks], kf, s[cb], 0, 0, 0);
            }
        }
        __builtin_amdgcn_s_setprio(0);

        // ---- online softmax with defer-max (THR=8) ----
        float tmax[4], mx = 0.f;
#pragma unroll
        for (int r = 0; r < 4; ++r) {
            float tm = fmaxf(fmaxf(s[0][r], s[1][r]), fmaxf(s[2][r], s[3][r]));
            tm = fmaxf(tm, __shfl_xor(tm, 1));
            tm = fmaxf(tm, __shfl_xor(tm, 2));
            tm = fmaxf(tm, __shfl_xor(tm, 4));
            tm = fmaxf(tm, __shfl_xor(tm, 8));
            tmax[r] = tm;
            mx = fmaxf(mx, tm - m[r]);
        }
        if (__any(mx > 8.f)) {  // rescale path (rare after warm-up)
#pragma unroll
            for (int r = 0; r < 4; ++r) {
                float mn = fmaxf(m[r], tmax[r]);
                float alpha = __expf(m[r] - mn);
                m[r] = mn;
                l[r] *= alpha;
#pragma unroll
                for (int dcb = 0; dcb < 8; ++dcb) O[dcb][r] *= alpha;
            }
        }
        float rs[4] = {0.f, 0.f, 0.f, 0.f};
#pragma unroll
        for (int cb = 0; cb < 4; ++cb)
#pragma unroll
            for (int r = 0; r < 4; ++r) {
                float p = __expf(s[cb][r] - m[r]);   // bounded by e^8
                rs[r] += p;
                int row = rg * 4 + r;
                int col = (cb * 16 + cl) ^ ((row & 7) << 3);  // chunk-XOR
                PsB[w * 1024 + row * 64 + col] = (__bf16)p;
            }
#pragma unroll
        for (int r = 0; r < 4; ++r) {
            float v = rs[r];
            v += __shfl_xor(v, 1);
            v += __shfl_xor(v, 2);
            v += __shfl_xor(v, 4);
            v += __shfl_xor(v, 8);
            l[r] += v;
        }
        // Ps is per-wave: same-wave ds write->read ordered by lgkmcnt waits.

        // ---- O += P @ V ----
        bf16x8 pf[2];
#pragma unroll
        for (int ks = 0; ks < 2; ++ks)
            pf[ks] = *reinterpret_cast<const bf16x8*>(
                PsB + w * 1024 + cl * 64 + (((ks * 4 + rg) ^ (cl & 7)) << 3));
        __builtin_amdgcn_s_setprio(1);
#pragma unroll
        for (int dcb = 0; dcb < 8; ++dcb) {
            const int row = dcb * 16 + cl;
            const __bf16* vr = Vb_ + row * 64;
            const int sw = row & 7;
#pragma unroll
            for (int ks = 0; ks < 2; ++ks) {
                bf16x8 vf = *reinterpret_cast<const bf16x8*>(
                    vr + (((ks * 4 + rg) ^ sw) << 3));
                O[dcb] = __builtin_amdgcn_mfma_f32_16x16x32_bf16(pf[ks], vf, O[dcb], 0, 0, 0);
            }
        }
        __builtin_amdgcn_s_setprio(0);

        // single barrier: drains next-tile DMA (vmcnt 0) + protects buf reuse
        __syncthreads();
        buf ^= 1;
    }
#undef STAGE_KV

    // ---- epilogue: normalize, transpose via LDS overlay, write T ----
    __bf16 (*Eb)[136] = reinterpret_cast<__bf16(*)[136]>(smem);
    float invl[4];
#pragma unroll
    for (int r = 0; r < 4; ++r) invl[r] = 1.0f / l[r];
    // O[dcb][r]: q-row = w*16 + rg*4 + r, d-col = dcb*16 + cl
#pragma unroll
    for (int dcb = 0; dcb < 8; ++dcb)
#pragma unroll
        for (int r = 0; r < 4; ++r)
            Eb[dcb * 16 + cl][w * 16 + rg * 4 + r] = (__bf16)(O[dcb][r] * invl[r]);
    __syncthreads();
    // write [128 d][128 s] tile: 2048 float4, 4 per thread
#pragma unroll
    for (int i = 0; i < 4; ++i) {
        int id = i * 512 + t;
        int d = id >> 4, c = id & 15;
        float4 v = *reinterpret_cast<const float4*>(&Eb[d][c * 8]);
        *reinterpret_cast<float4*>(
            T + (size_t)(b * HDIM + nh * HD + d) * SLEN + q0 + c * 8) = v;
    }
}

// ---------------------------------------------------------------------------
extern "C" void kernel_launch(void* const* d_in, const int* in_sizes, int n_in,
                              void* d_out, int out_size, void* d_ws, size_t ws_size,
                              hipStream_t stream) {
    const float* hs  = (const float*)d_in[0];
    const float* w_q = (const float*)d_in[1];
    const float* b_q = (const float*)d_in[2];
    const float* w_k = (const float*)d_in[3];
    const float* b_k = (const float*)d_in[4];
    const float* w_v = (const float*)d_in[5];
    const float* b_v = (const float*)d_in[6];
    const float* w_o = (const float*)d_in[7];
    const float* b_o = (const float*)d_in[8];

    const int M = BATCH * SLEN;          // 8192
    const size_t MH = (size_t)M * HDIM;  // 16.8M

    // d_out (67.1 MB) partition: [hs_bf16 33.55MB][Q 33.55MB]
    __bf16* hs_b = (__bf16*)d_out;
    __bf16* Qb   = hs_b + MH;

    // ws partition (wkT and wvT contiguous -> fused KV B^T of 256 rows)
    char* p = (char*)d_ws;
    __bf16* wqT = (__bf16*)p;             p += (size_t)HDIM * HDIM * 2;  // 8.39MB
    __bf16* woT = (__bf16*)p;             p += (size_t)HDIM * HDIM * 2;  // 8.39MB
    __bf16* wkT = (__bf16*)p;             p += (size_t)HD * HDIM * 2;    // 0.52MB
    __bf16* wvT = (__bf16*)p;             p += (size_t)HD * HDIM * 2;    // 0.52MB
    __bf16* Kb  = (__bf16*)p;             p += (size_t)M * HD * 2;       // 2.10MB
    __bf16* VTb = (__bf16*)p;             p += (size_t)M * HD * 2;       // 2.10MB
    __bf16* Tb  = (__bf16*)p;                                            // 33.55MB

    dim3 blk(256);

    // converts
    conv_bf16<<<dim3(MH / (256 * 8)), blk, 0, stream>>>(hs, hs_b);
    transpose_conv<<<dim3(HDIM / 32, HDIM / 32), blk, 0, stream>>>(w_q, wqT, HDIM, HDIM);
    transpose_conv<<<dim3(HD / 32, HDIM / 32), blk, 0, stream>>>(w_k, wkT, HDIM, HD);
    transpose_conv<<<dim3(HD / 32, HDIM / 32), blk, 0, stream>>>(w_v, wvT, HDIM, HD);
    transpose_conv<<<dim3(HDIM / 32, HDIM / 32), blk, 0, stream>>>(w_o, woT, HDIM, HDIM);

    // projections (1D grids, XCD-swizzled)
    gemm_bt<1><<<dim3(16 * (M / 128)), blk, 0, stream>>>(
        hs_b, wqT, b_q, nullptr, Qb, nullptr, M, HDIM, HDIM, 16);
    // fused K+V projection: B^T = [wkT | wvT] (256 rows); V written as VT
    gemm_bt<3><<<dim3(2 * (M / 128)), blk, 0, stream>>>(
        hs_b, wkT, b_k, b_v, Kb, VTb, M, 2 * HD, HDIM, 2);

    // attention (QBLK=128, 8 waves, dbuf)
    mqa_attn_mfma<<<dim3(BATCH * NHEADS * (SLEN / 128)), dim3(512), 0, stream>>>(
        Qb, Kb, VTb, Tb);

    // output projection (contracts over seq via T layout)
    gemm_bt<0><<<dim3(16 * (M / 128)), blk, 0, stream>>>(
        Tb, woT, b_o, nullptr, d_out, nullptr, M, HDIM, HDIM, 16);
}

// Round 12
// 567.007 us; speedup vs baseline: 8.8762x; 1.1358x over previous
//
#include <hip/hip_runtime.h>
#include <math.h>

// MQA bf16-MFMA pipeline. B=4, S=2048, H=2048, NH=16, HD=128.
//  conv:  hs f32 -> hs_bf16 (d_out lo half)
//  convT: w_q/w_k/w_v/w_o f32 [K][N] -> bf16 [N][K] (ws; wq|wk|wv contiguous)
//  P1: mega-projection (MODE 4): Q -> d_out hi, K -> ws, V -> VT[b][d][s] (ws)
//  P4: flash attn (MFMA, QBLK=128, 8 waves, dbuf K/V, lazy-max, deferred-l)
//      -> T[b][nh*128+d][s] bf16 (ws)
//  P5: out = T @ w_o + b_o  f32 -> d_out

#define BATCH 4
#define SLEN 2048
#define HDIM 2048
#define NHEADS 16
#define HD 128

typedef __bf16 bf16x8 __attribute__((ext_vector_type(8)));
typedef float f32x4 __attribute__((ext_vector_type(4)));

__device__ __forceinline__ void gload_lds16(const void* g, void* l) {
    __builtin_amdgcn_global_load_lds(
        (const __attribute__((address_space(1))) void*)g,
        (__attribute__((address_space(3))) void*)l, 16, 0, 0);
}

// bijective XCD-chunked swizzle; requires nwg % 8 == 0
__device__ __forceinline__ int xcd_swizzle(int bid, int nwg) {
    int cpx = nwg >> 3;
    return (bid & 7) * cpx + (bid >> 3);
}

// ---------------------------------------------------------------------------
// conv: f32 -> bf16, 8 elems/thread
// ---------------------------------------------------------------------------
__global__ void conv_bf16(const float* __restrict__ in, __bf16* __restrict__ out) {
    int i = (blockIdx.x * 256 + threadIdx.x) * 8;
    float4 a = *reinterpret_cast<const float4*>(in + i);
    float4 b = *reinterpret_cast<const float4*>(in + i + 4);
    bf16x8 o;
    o[0] = (__bf16)a.x; o[1] = (__bf16)a.y; o[2] = (__bf16)a.z; o[3] = (__bf16)a.w;
    o[4] = (__bf16)b.x; o[5] = (__bf16)b.y; o[6] = (__bf16)b.z; o[7] = (__bf16)b.w;
    *reinterpret_cast<bf16x8*>(out + i) = o;
}

// ---------------------------------------------------------------------------
// transpose+convert: in f32 [R][C] -> out bf16 [C][R]
// ---------------------------------------------------------------------------
__global__ void transpose_conv(const float* __restrict__ in, __bf16* __restrict__ out,
                               int R, int C) {
    __shared__ float tile[32][33];
    int c0 = blockIdx.x * 32, r0 = blockIdx.y * 32;
    int tr = threadIdx.x >> 5, tc = threadIdx.x & 31;
#pragma unroll
    for (int i = 0; i < 4; ++i)
        tile[tr + i * 8][tc] = in[(size_t)(r0 + tr + i * 8) * C + c0 + tc];
    __syncthreads();
#pragma unroll
    for (int i = 0; i < 4; ++i)
        out[(size_t)(c0 + tr + i * 8) * R + r0 + tc] = (__bf16)tile[tc][tr + i * 8];
}

// ---------------------------------------------------------------------------
// bf16 GEMM (m97 structure): C[M][N] = A[M][K] @ BT[N][K]^T + bias
// 128x128 tile, BK=64, 4 waves (2x2). 1D grid + XCD swizzle.
// MODE 0: f32 out (stride N).
// MODE 4: mega-projection, N = 2304 = [Q 2048 | K 128 | V 128]:
//   col<2048        -> Q bf16 [row][col]          (bias  = b_q)
//   2048<=col<2176  -> K bf16 [row][col-2048]     (bias2 = b_k)
//   col>=2176       -> VT bf16 [b][col-2176][s]   (bias3 = b_v), row = b*SLEN+s
// ---------------------------------------------------------------------------
template <int MODE>
__global__ __launch_bounds__(256) void gemm_bt(
    const __bf16* __restrict__ A, const __bf16* __restrict__ BT,
    const float* __restrict__ bias, const float* __restrict__ bias2,
    const float* __restrict__ bias3,
    void* __restrict__ Cout, void* __restrict__ Cout2, void* __restrict__ Cout3,
    int M, int N, int K, int nbx)
{
    __shared__ __bf16 As[128 * 64];
    __shared__ __bf16 Bs[128 * 64];
    const int t = threadIdx.x;
    const int lane = t & 63;
    const int w = t >> 6;
    const int wr = w >> 1, wc = w & 1;
    const int id = xcd_swizzle(blockIdx.x, gridDim.x);
    const int m0 = (id / nbx) << 7, n0 = (id % nbx) << 7;

    f32x4 acc[4][4] = {};
    const int l8 = (lane & 7) * 8;   // k-offset (elems) within chunk row
    const int lr = lane >> 3;        // row-in-chunk

    for (int k0 = 0; k0 < K; k0 += 64) {
        __syncthreads();
#pragma unroll
        for (int i = 0; i < 4; ++i) {
            int c = w * 4 + i;
            int row = c * 8 + lr;
            gload_lds16(A + (size_t)(m0 + row) * K + k0 + l8, (char*)As + c * 1024);
            gload_lds16(BT + (size_t)(n0 + row) * K + k0 + l8, (char*)Bs + c * 1024);
        }
        __syncthreads();
#pragma unroll
        for (int ks = 0; ks < 2; ++ks) {
            bf16x8 a[4], b[4];
#pragma unroll
            for (int i = 0; i < 4; ++i) {
                a[i] = *reinterpret_cast<const bf16x8*>(
                    As + (wr * 64 + i * 16 + (lane & 15)) * 64 + ks * 32 + (lane >> 4) * 8);
                b[i] = *reinterpret_cast<const bf16x8*>(
                    Bs + (wc * 64 + i * 16 + (lane & 15)) * 64 + ks * 32 + (lane >> 4) * 8);
            }
#pragma unroll
            for (int i = 0; i < 4; ++i)
#pragma unroll
                for (int j = 0; j < 4; ++j)
                    acc[i][j] = __builtin_amdgcn_mfma_f32_16x16x32_bf16(
                        a[i], b[j], acc[i][j], 0, 0, 0);
        }
    }

    const int col_l = lane & 15, rgrp = lane >> 4;
#pragma unroll
    for (int j = 0; j < 4; ++j) {
        int col = n0 + wc * 64 + j * 16 + col_l;
        float bv;
        if (MODE == 4)
            bv = (col < HDIM) ? bias[col]
               : (col < HDIM + HD) ? bias2[col - HDIM]
               : bias3[col - HDIM - HD];
        else
            bv = bias[col];
#pragma unroll
        for (int i = 0; i < 4; ++i) {
            int rowb = m0 + wr * 64 + i * 16 + rgrp * 4;
#pragma unroll
            for (int r = 0; r < 4; ++r) {
                float v = acc[i][j][r] + bv;
                int row = rowb + r;
                if (MODE == 0)
                    ((float*)Cout)[(size_t)row * N + col] = v;
                else {  // MODE 4
                    if (col < HDIM)
                        ((__bf16*)Cout)[(size_t)row * HDIM + col] = (__bf16)v;
                    else if (col < HDIM + HD)
                        ((__bf16*)Cout2)[(size_t)row * HD + (col - HDIM)] = (__bf16)v;
                    else
                        ((__bf16*)Cout3)[((size_t)(row >> 11) * HD + (col - HDIM - HD)) * SLEN
                                         + (row & (SLEN - 1))] = (__bf16)v;
                }
            }
        }
    }
}

// ---------------------------------------------------------------------------
// Flash attention, bf16 MFMA. Block = (b, nh, q-tile of 128). 8 waves, each
// owns 16 q-rows. KV tile = 64, double-buffered, 1 barrier/iter. Pre-swizzled
// DMA source + XOR reads. Softmax: scale folded into Q; LAZY MAX (per-lane
// guard + __any vote, cross-lane max-reduce only on trigger); DEFERRED l
// (per-lane partial sums in regs, single reduce in the epilogue). Common-path
// cross-lane DS ops per iter: zero.
// ---------------------------------------------------------------------------
__attribute__((amdgpu_waves_per_eu(2, 4)))
__global__ __launch_bounds__(512) void mqa_attn_mfma(
    const __bf16* __restrict__ Q,   // [8192][2048]
    const __bf16* __restrict__ K,   // [8192][128]
    const __bf16* __restrict__ VT,  // [4][128][2048]
    __bf16* __restrict__ T)         // [4][2048][2048]
{
    // LDS (bf16 elems): K bufs 2x8192 @0 | V bufs 2x8192 @16384
    //                   | Ps 8x16x64 @32768  => 40960 elems = 80 KB exactly.
    // Epilogue overlays Eb[128][136] (34.8 KB) at 0 after the final barrier.
    __shared__ __align__(16) __bf16 smem[40960];
    __bf16* KsB = smem;            // per-buf 8192 elems; row stride 128
    __bf16* VtB = smem + 16384;    // per-buf 8192 elems; row stride 64
    __bf16* PsB = smem + 32768;    // per-wave 1024 elems; row stride 64, XOR-chunk

    const int t = threadIdx.x;
    const int lane = t & 63;
    const int w = t >> 6;            // 0..7
    const int bid = xcd_swizzle(blockIdx.x, gridDim.x);
    const int qb = bid & 15;         // 16 q-tiles of 128
    const int nh = (bid >> 4) & 15;
    const int b = bid >> 8;
    const int q0 = qb << 7;

    const int cl = lane & 15;        // col-in-frag / A-row
    const int rg = lane >> 4;        // k-group / C-row-group

    const float scale = 0.08838834764831845f;  // 1/sqrt(128)

    // Q fragments, scale pre-folded
    bf16x8 qf[4];
    {
        const __bf16* qrow = Q + (size_t)(b * SLEN + q0 + w * 16 + cl) * HDIM
                             + nh * HD + rg * 8;
#pragma unroll
        for (int ks = 0; ks < 4; ++ks) {
            bf16x8 raw = *reinterpret_cast<const bf16x8*>(qrow + ks * 32);
#pragma unroll
            for (int j = 0; j < 8; ++j)
                qf[ks][j] = (__bf16)((float)raw[j] * scale);
        }
    }

    f32x4 O[8] = {};
    float m[4], lacc[4];
#pragma unroll
    for (int r = 0; r < 4; ++r) { m[r] = -__builtin_inff(); lacc[r] = 0.f; }

    // per-lane swizzled staging geometry (constant across iters)
    const int k_row0 = (w * 2) * 4 + (lane >> 4);      // j adds 4
    const int k_cc0  = lane & 15;
    const int v_row0 = (w * 2) * 8 + (lane >> 3);      // j adds 8
    const int v_cc0  = lane & 7;

#define STAGE_KV(TILE, BUF)                                                     \
    do {                                                                        \
        int kk_ = (TILE) * 64;                                                  \
        _Pragma("unroll")                                                       \
        for (int j = 0; j < 2; ++j) {                                           \
            int idx = w * 2 + j;                                                \
            int row = k_row0 + j * 4;                                           \
            int cc  = k_cc0 ^ (row & 7);                                        \
            gload_lds16(K + (size_t)(b * SLEN + kk_ + row) * HD + cc * 8,       \
                        (char*)(KsB + (BUF) * 8192) + idx * 1024);              \
        }                                                                       \
        _Pragma("unroll")                                                       \
        for (int j = 0; j < 2; ++j) {                                           \
            int idx = w * 2 + j;                                                \
            int row = v_row0 + j * 8;                                           \
            int cc  = v_cc0 ^ (row & 7);                                        \
            gload_lds16(VT + (size_t)(b * HD + row) * SLEN + kk_ + cc * 8,      \
                        (char*)(VtB + (BUF) * 8192) + idx * 1024);              \
        }                                                                       \
    } while (0)

    // prologue: stage tile 0
    STAGE_KV(0, 0);
    __syncthreads();

    int buf = 0;
    const int NT = SLEN / 64;  // 32
    for (int tt = 0; tt < NT; ++tt) {
        // issue next tile's DMA into the other buffer (overlaps compute below)
        if (tt + 1 < NT) STAGE_KV(tt + 1, buf ^ 1);

        const __bf16* Kb_ = KsB + buf * 8192;
        const __bf16* Vb_ = VtB + buf * 8192;

        // ---- S = (Q*scale) K^T (per wave: 16 x 64) ----
        f32x4 s[4] = {};
        __builtin_amdgcn_s_setprio(1);
#pragma unroll
        for (int cb = 0; cb < 4; ++cb) {
            const int row = cb * 16 + cl;
            const __bf16* kr = Kb_ + row * 128;
            const int sw = row & 7;
#pragma unroll
            for (int ks = 0; ks < 4; ++ks) {
                bf16x8 kf = *reinterpret_cast<const bf16x8*>(
                    kr + (((ks * 4 + rg) ^ sw) << 3));
                s[cb] = __builtin_amdgcn_mfma_f32_16x16x32_bf16(qf[ks], kf, s[cb], 0, 0, 0);
            }
        }
        __builtin_amdgcn_s_setprio(0);

        // ---- softmax: lazy max (no cross-lane reduce in common path) ----
        float lmax[4];
        float mx = -1e30f;
#pragma unroll
        for (int r = 0; r < 4; ++r) {
            float tm = fmaxf(fmaxf(s[0][r], s[1][r]), fmaxf(s[2][r], s[3][r]));
            lmax[r] = tm;
            mx = fmaxf(mx, tm - m[r]);
        }
        if (__any(mx > 8.f)) {  // exact path (first iter + rare growth)
#pragma unroll
            for (int r = 0; r < 4; ++r) {
                float tm = lmax[r];
                tm = fmaxf(tm, __shfl_xor(tm, 1));
                tm = fmaxf(tm, __shfl_xor(tm, 2));
                tm = fmaxf(tm, __shfl_xor(tm, 4));
                tm = fmaxf(tm, __shfl_xor(tm, 8));
                float mn = fmaxf(m[r], tm);
                float alpha = __expf(m[r] - mn);
                m[r] = mn;
                lacc[r] *= alpha;   // per-lane partials scale exactly
#pragma unroll
                for (int dcb = 0; dcb < 8; ++dcb) O[dcb][r] *= alpha;
            }
        }
#pragma unroll
        for (int cb = 0; cb < 4; ++cb)
#pragma unroll
            for (int r = 0; r < 4; ++r) {
                float p = __expf(s[cb][r] - m[r]);   // bounded by e^8
                lacc[r] += p;                        // deferred-l partial
                int row = rg * 4 + r;
                int col = (cb * 16 + cl) ^ ((row & 7) << 3);  // chunk-XOR
                PsB[w * 1024 + row * 64 + col] = (__bf16)p;
            }
        // Ps is per-wave: same-wave ds write->read ordered by lgkmcnt waits.

        // ---- O += P @ V ----
        bf16x8 pf[2];
#pragma unroll
        for (int ks = 0; ks < 2; ++ks)
            pf[ks] = *reinterpret_cast<const bf16x8*>(
                PsB + w * 1024 + cl * 64 + (((ks * 4 + rg) ^ (cl & 7)) << 3));
        __builtin_amdgcn_s_setprio(1);
#pragma unroll
        for (int dcb = 0; dcb < 8; ++dcb) {
            const int row = dcb * 16 + cl;
            const __bf16* vr = Vb_ + row * 64;
            const int sw = row & 7;
#pragma unroll
            for (int ks = 0; ks < 2; ++ks) {
                bf16x8 vf = *reinterpret_cast<const bf16x8*>(
                    vr + (((ks * 4 + rg) ^ sw) << 3));
                O[dcb] = __builtin_amdgcn_mfma_f32_16x16x32_bf16(pf[ks], vf, O[dcb], 0, 0, 0);
            }
        }
        __builtin_amdgcn_s_setprio(0);

        // single barrier: drains next-tile DMA (vmcnt 0) + protects buf reuse
        __syncthreads();
        buf ^= 1;
    }
#undef STAGE_KV

    // ---- epilogue: reduce l, normalize, transpose via LDS overlay, write T ----
    float invl[4];
#pragma unroll
    for (int r = 0; r < 4; ++r) {
        float v = lacc[r];
        v += __shfl_xor(v, 1);
        v += __shfl_xor(v, 2);
        v += __shfl_xor(v, 4);
        v += __shfl_xor(v, 8);
        invl[r] = 1.0f / v;
    }
    __bf16 (*Eb)[136] = reinterpret_cast<__bf16(*)[136]>(smem);
    // O[dcb][r]: q-row = w*16 + rg*4 + r, d-col = dcb*16 + cl
#pragma unroll
    for (int dcb = 0; dcb < 8; ++dcb)
#pragma unroll
        for (int r = 0; r < 4; ++r)
            Eb[dcb * 16 + cl][w * 16 + rg * 4 + r] = (__bf16)(O[dcb][r] * invl[r]);
    __syncthreads();
    // write [128 d][128 s] tile: 2048 float4, 4 per thread
#pragma unroll
    for (int i = 0; i < 4; ++i) {
        int id = i * 512 + t;
        int d = id >> 4, c = id & 15;
        float4 v = *reinterpret_cast<const float4*>(&Eb[d][c * 8]);
        *reinterpret_cast<float4*>(
            T + (size_t)(b * HDIM + nh * HD + d) * SLEN + q0 + c * 8) = v;
    }
}

// ---------------------------------------------------------------------------
extern "C" void kernel_launch(void* const* d_in, const int* in_sizes, int n_in,
                              void* d_out, int out_size, void* d_ws, size_t ws_size,
                              hipStream_t stream) {
    const float* hs  = (const float*)d_in[0];
    const float* w_q = (const float*)d_in[1];
    const float* b_q = (const float*)d_in[2];
    const float* w_k = (const float*)d_in[3];
    const float* b_k = (const float*)d_in[4];
    const float* w_v = (const float*)d_in[5];
    const float* b_v = (const float*)d_in[6];
    const float* w_o = (const float*)d_in[7];
    const float* b_o = (const float*)d_in[8];

    const int M = BATCH * SLEN;          // 8192
    const size_t MH = (size_t)M * HDIM;  // 16.8M

    // d_out (67.1 MB) partition: [hs_bf16 33.55MB][Q 33.55MB]
    __bf16* hs_b = (__bf16*)d_out;
    __bf16* Qb   = hs_b + MH;

    // ws partition: wqT|wkT|wvT CONTIGUOUS (mega-projection B^T, 2304 rows)
    char* p = (char*)d_ws;
    __bf16* wqT = (__bf16*)p;             p += (size_t)HDIM * HDIM * 2;  // 8.39MB
    __bf16* wkT = (__bf16*)p;             p += (size_t)HD * HDIM * 2;    // 0.52MB
    __bf16* wvT = (__bf16*)p;             p += (size_t)HD * HDIM * 2;    // 0.52MB
    __bf16* woT = (__bf16*)p;             p += (size_t)HDIM * HDIM * 2;  // 8.39MB
    __bf16* Kb  = (__bf16*)p;             p += (size_t)M * HD * 2;       // 2.10MB
    __bf16* VTb = (__bf16*)p;             p += (size_t)M * HD * 2;       // 2.10MB
    __bf16* Tb  = (__bf16*)p;                                            // 33.55MB

    dim3 blk(256);

    // converts
    conv_bf16<<<dim3(MH / (256 * 8)), blk, 0, stream>>>(hs, hs_b);
    transpose_conv<<<dim3(HDIM / 32, HDIM / 32), blk, 0, stream>>>(w_q, wqT, HDIM, HDIM);
    transpose_conv<<<dim3(HD / 32, HDIM / 32), blk, 0, stream>>>(w_k, wkT, HDIM, HD);
    transpose_conv<<<dim3(HD / 32, HDIM / 32), blk, 0, stream>>>(w_v, wvT, HDIM, HD);
    transpose_conv<<<dim3(HDIM / 32, HDIM / 32), blk, 0, stream>>>(w_o, woT, HDIM, HDIM);

    // mega-projection: Q + K + V in one launch (N = 2304, 1152 wgs)
    gemm_bt<4><<<dim3(18 * (M / 128)), blk, 0, stream>>>(
        hs_b, wqT, b_q, b_k, b_v, Qb, Kb, VTb, M, 2304, HDIM, 18);

    // attention (QBLK=128, 8 waves, dbuf, lazy-max, deferred-l)
    mqa_attn_mfma<<<dim3(BATCH * NHEADS * (SLEN / 128)), dim3(512), 0, stream>>>(
        Qb, Kb, VTb, Tb);

    // output projection (contracts over seq via T layout)
    gemm_bt<0><<<dim3(16 * (M / 128)), blk, 0, stream>>>(
        Tb, woT, b_o, nullptr, nullptr, d_out, nullptr, nullptr, M, HDIM, HDIM, 16);
}